// Round 13
// baseline (167.232 us; speedup 1.0000x reference)
//
#include <hip/hip_runtime.h>
#include <hip/hip_bf16.h>

#define EPSV 1e-5f
typedef __hip_bfloat16 bf16;
typedef __attribute__((ext_vector_type(8))) short v8s;
typedef __attribute__((ext_vector_type(4))) float v4f;
__device__ __forceinline__ float b2f(bf16 v) { return __bfloat162float(v); }
__device__ __forceinline__ bf16 f2b(float v) { return __float2bfloat16(v); }
__device__ __forceinline__ float bs2f(short s) {
  return __uint_as_float(((unsigned)(unsigned short)s) << 16);
}
__device__ __forceinline__ short f2bs(float v) {
  bf16 b = __float2bfloat16(v);
  return *(short*)&b;
}

__global__ __launch_bounds__(256) void fill_k(float* __restrict__ out, float val, int n)
{
  int i = blockIdx.x * 256 + threadIdx.x;
  if (i < n) out[i] = val;
}

// ---------- setup: zero accum/cnt; pack w2b/w3b TRANSPOSED [oc][s*32+ic]; Web; Wob ----------
__global__ __launch_bounds__(256) void setup_k(
    const float* __restrict__ w2, const float* __restrict__ w3,
    const float* __restrict__ We, const float* __restrict__ Wo,
    bf16* __restrict__ w2b, bf16* __restrict__ w3b,
    bf16* __restrict__ Web, bf16* __restrict__ Wob,
    int* __restrict__ cnt27, float* __restrict__ Macc,
    float* __restrict__ Sacc2, float* __restrict__ Sacc3)
{
  int i = blockIdx.x * 256 + threadIdx.x;
  if (i < 64) {
    cnt27[i] = 0;
    Macc[i] = 0.f;
    Sacc2[i] = 0.f;
    Sacc3[i] = 0.f;
  }
  if (i < 9216) {
    int oc = i / 288, r = i - oc * 288, s = r >> 5, ic = r & 31;  // [oc][s*32+ic]
    w2b[i] = f2b(w2[oc * 288 + ic * 9 + s]);
  } else if (i < 18432) {
    int j = i - 9216;
    int oc = j / 288, r = j - oc * 288, s = r >> 5, ic = r & 31;
    w3b[j] = f2b(w3[oc * 288 + ic * 9 + s]);
  } else if (i < 18432 + 49152) {
    Web[i - 18432] = f2b(We[i - 18432]);
  } else if (i < 18432 + 49152 + 2048) {
    int j = i - 18432 - 49152;               // j = k*16 + o
    int k = j >> 4, o = j & 15;
    Wob[j] = (o < 10) ? f2b(Wo[o * 128 + k]) : f2b(0.f);
  }
}

// ---------- front: blocks 0-31 = signature compaction; 32-543 = conv1 autocorr ----------
__global__ __launch_bounds__(256) void front_k(
    const float* __restrict__ traj, const float* __restrict__ x,
    int* __restrict__ cnt27, int* __restrict__ lists, float* __restrict__ Macc)
{
  int t = threadIdx.x;
  if (blockIdx.x < 32) {
    int row = blockIdx.x * 256 + t;
    __shared__ int lcnt[64], lbase[64];
    if (t < 64) lcnt[t] = 0;
    __syncthreads();
    int e[3];
#pragma unroll
    for (int s = 0; s < 3; ++s) {
      float4 tv = ((const float4*)traj)[s * 8192 + row];
      int ee = 0; float bv = tv.x;
      if (tv.y > bv) { bv = tv.y; ee = 1; }
      if (tv.z > bv) { bv = tv.z; ee = 2; }
      if (tv.w > bv) { bv = tv.w; ee = 3; }
      e[s] = ee;
    }
    int sig = e[0] + 4 * e[1] + 16 * e[2];
    int my = atomicAdd(&lcnt[sig], 1);
    __syncthreads();
    if (t < 64) lbase[t] = atomicAdd(&cnt27[t], lcnt[t]);
    __syncthreads();
    lists[sig * 8192 + lbase[sig] + my] = row;
    return;
  }
  // conv1 autocorrelation: 4 images per block
  int blk = blockIdx.x - 32;
  __shared__ __align__(16) float xs[1024];
  float M[45], S[9];
#pragma unroll
  for (int k = 0; k < 45; ++k) M[k] = 0.f;
#pragma unroll
  for (int k = 0; k < 9; ++k) S[k] = 0.f;
  for (int im = 0; im < 4; ++im) {
    int img = blk * 4 + im;
    ((float4*)xs)[t] = ((const float4*)(x + img * 1024))[t];
    __syncthreads();
    for (int p = t; p < 900; p += 256) {
      int y = p / 30, xx = p - y * 30;
      const float* r0 = xs + y * 32 + xx;
      float v[9];
      v[0] = r0[0];  v[1] = r0[1];  v[2] = r0[2];
      v[3] = r0[32]; v[4] = r0[33]; v[5] = r0[34];
      v[6] = r0[64]; v[7] = r0[65]; v[8] = r0[66];
      int idx = 0;
#pragma unroll
      for (int i = 0; i < 9; ++i) {
        S[i] += v[i];
#pragma unroll
        for (int j = i; j < 9; ++j) M[idx++] = fmaf(v[i], v[j], M[idx]);
      }
    }
    __syncthreads();
  }
  float a[54];
#pragma unroll
  for (int k = 0; k < 45; ++k) a[k] = M[k];
#pragma unroll
  for (int k = 0; k < 9; ++k) a[45 + k] = S[k];
#pragma unroll
  for (int k = 0; k < 54; ++k) {
#pragma unroll
    for (int off = 32; off; off >>= 1) a[k] += __shfl_down(a[k], off, 64);
  }
  __shared__ float red[4][54];
  int wv = t >> 6, lane = t & 63;
  if (lane == 0) {
#pragma unroll
    for (int k = 0; k < 54; ++k) red[wv][k] = a[k];
  }
  __syncthreads();
  if (t < 54)
    atomicAdd(&Macc[t], red[0][t] + red[1][t] + red[2][t] + red[3][t]);
}

// ---------- conv1 apply: inline BN params from autocorr sums ----------
__global__ __launch_bounds__(256) void conv1_apply_k(
    const float* __restrict__ x, const float* __restrict__ w1,
    const float* __restrict__ b1, const float* __restrict__ g,
    const float* __restrict__ bt, const float* __restrict__ Macc,
    bf16* __restrict__ pooled1)
{
  int img = blockIdx.x, t = threadIdx.x;
  __shared__ __align__(16) float xs[1024];
  ((float4*)xs)[t] = ((const float4*)(x + img * 1024))[t];
  __syncthreads();
  int c = t & 31;
  float w[9];
#pragma unroll
  for (int j = 0; j < 9; ++j) w[j] = w1[c * 9 + j];
  float bias = b1[c];
  float wS = 0.f;
#pragma unroll
  for (int i = 0; i < 9; ++i) wS = fmaf(w[i], Macc[45 + i], wS);
  float wMw = 0.f;
  {
    int idx = 0;
#pragma unroll
    for (int i = 0; i < 9; ++i)
#pragma unroll
      for (int j = i; j < 9; ++j) {
        float coef = (i == j) ? 1.f : 2.f;
        wMw = fmaf(coef * w[i] * w[j], Macc[idx], wMw);
        ++idx;
      }
  }
  const float Np = 2048.f * 900.f;
  float mean = (wS + Np * bias) / Np;
  float sumsq = wMw + 2.f * bias * wS + Np * bias * bias;
  float var = sumsq / Np - mean * mean;
  float sc = g[c] / sqrtf(var + EPSV);
  float sh = bt[c] - mean * sc;

  bf16* outp = pooled1 + img * 7200;
  for (int idx = t; idx < 7200; idx += 256) {
    int pp = idx >> 5;
    int py = pp / 15, px = pp - py * 15;
    int y0 = 2 * py, x0 = 2 * px;
    float rv[4][4];
#pragma unroll
    for (int rr = 0; rr < 4; ++rr) {
      float2 lo = *(const float2*)(xs + (y0 + rr) * 32 + x0);
      float2 hi = *(const float2*)(xs + (y0 + rr) * 32 + x0 + 2);
      rv[rr][0] = lo.x; rv[rr][1] = lo.y; rv[rr][2] = hi.x; rv[rr][3] = hi.y;
    }
    float r = 0.f;
#pragma unroll
    for (int i = 0; i < 2; ++i)
#pragma unroll
      for (int j = 0; j < 2; ++j) {
        float v = bias;
        v = fmaf(rv[i][j],     w[0], v); v = fmaf(rv[i][j + 1],     w[1], v); v = fmaf(rv[i][j + 2],     w[2], v);
        v = fmaf(rv[i + 1][j], w[3], v); v = fmaf(rv[i + 1][j + 1], w[4], v); v = fmaf(rv[i + 1][j + 2], w[5], v);
        v = fmaf(rv[i + 2][j], w[6], v); v = fmaf(rv[i + 2][j + 1], w[7], v); v = fmaf(rv[i + 2][j + 2], w[8], v);
        r += fmaxf(fmaf(v, sc, sh), 0.f);
      }
    outp[idx] = f2b(r * 0.25f);
  }
}

// ---------- implicit-GEMM conv via MFMA; transposed weights -> 18 v8s prologue loads ----------
template <int IN_W, int OUT_W, int OUT_PIX, bool OUT_BF16>
__global__ __launch_bounds__(256) void conv_mfma_k(
    const bf16* __restrict__ in, const bf16* __restrict__ wb,
    void* __restrict__ outv, float* __restrict__ sacc, int ntiles)
{
  constexpr int IN_PIX = IN_W * IN_W;
  int t = threadIdx.x, lane = t & 63;
  int m = lane & 15, kg = lane >> 4;
  const short* wbs = (const short*)wb;
  v8s bfr[9][2];
#pragma unroll
  for (int s = 0; s < 9; ++s)
#pragma unroll
    for (int ob = 0; ob < 2; ++ob)
      bfr[s][ob] = *(const v8s*)(wbs + (ob * 16 + m) * 288 + s * 32 + kg * 8);

  float rs0 = 0.f, rss0 = 0.f, rs1 = 0.f, rss1 = 0.f;
  int gwave = blockIdx.x * 4 + (t >> 6);
  int nw = gridDim.x * 4;
  for (int tile = gwave; tile < ntiles; tile += nw) {
    unsigned p = tile * 16 + m;
    unsigned img = p / OUT_PIX, pix = p - img * OUT_PIX;
    unsigned y = pix / OUT_W, x = pix - y * OUT_W;
    const bf16* ap = in + img * (IN_PIX * 32) + (y * IN_W + x) * 32 + kg * 8;
    v4f acc0 = {0.f, 0.f, 0.f, 0.f}, acc1 = {0.f, 0.f, 0.f, 0.f};
#pragma unroll
    for (int ky = 0; ky < 3; ++ky)
#pragma unroll
      for (int kx = 0; kx < 3; ++kx) {
        v8s a = *(const v8s*)(ap + (ky * IN_W + kx) * 32);
        acc0 = __builtin_amdgcn_mfma_f32_16x16x32_bf16(a, bfr[ky * 3 + kx][0], acc0, 0, 0, 0);
        acc1 = __builtin_amdgcn_mfma_f32_16x16x32_bf16(a, bfr[ky * 3 + kx][1], acc1, 0, 0, 0);
      }
    // C rows are globally pixel-contiguous: out index = pr*32 + ch
#pragma unroll
    for (int j = 0; j < 4; ++j) {
      rs0 += acc0[j]; rss0 = fmaf(acc0[j], acc0[j], rss0);
      rs1 += acc1[j]; rss1 = fmaf(acc1[j], acc1[j], rss1);
      unsigned pr = tile * 16 + kg * 4 + j;
      unsigned base = pr * 32;
      if (OUT_BF16) {
        bf16* o = (bf16*)outv;
        o[base + m] = f2b(acc0[j]);
        o[base + 16 + m] = f2b(acc1[j]);
      } else {
        float* o = (float*)outv;
        o[base + m] = acc0[j];
        o[base + 16 + m] = acc1[j];
      }
    }
  }
  rs0 += __shfl_xor(rs0, 16, 64);  rss0 += __shfl_xor(rss0, 16, 64);
  rs0 += __shfl_xor(rs0, 32, 64);  rss0 += __shfl_xor(rss0, 32, 64);
  rs1 += __shfl_xor(rs1, 16, 64);  rss1 += __shfl_xor(rss1, 16, 64);
  rs1 += __shfl_xor(rs1, 32, 64);  rss1 += __shfl_xor(rss1, 32, 64);
  __shared__ float red[4][32][2];
  int wv = t >> 6;
  if (lane < 16) {
    red[wv][lane][0] = rs0;      red[wv][lane][1] = rss0;
    red[wv][16 + lane][0] = rs1; red[wv][16 + lane][1] = rss1;
  }
  __syncthreads();
  if (t < 64) {
    int cc = t >> 1, j = t & 1;
    atomicAdd(&sacc[t], red[0][cc][j] + red[1][cc][j] + red[2][cc][j] + red[3][cc][j]);
  }
}

// ---------- conv2 apply: inline bnp2 from Sacc2; BN+ReLU+pool -> NHWC bf16 ----------
__global__ __launch_bounds__(256) void conv2_apply_k(
    const bf16* __restrict__ in, const float* __restrict__ Sacc2,
    const float* __restrict__ g, const float* __restrict__ bt,
    bf16* __restrict__ out)
{
  int idx = blockIdx.x * 256 + threadIdx.x;  // exactly 2048*36*4
  int img = idx / 144, r = idx - img * 144;
  int pp = r >> 2, c8 = r & 3;
  int py = pp / 6, px = pp - py * 6;
  int ip0 = (2 * py) * 13 + 2 * px;
  const bf16* bp = in + (img * 169 + ip0) * 32 + c8 * 8;
  v8s a = *(const v8s*)bp;
  v8s b = *(const v8s*)(bp + 32);
  v8s cc = *(const v8s*)(bp + 13 * 32);
  v8s d = *(const v8s*)(bp + 14 * 32);
  const float invn = 1.f / (2048.f * 169.f);
  union { v8s v; short s[8]; bf16 h[8]; } res;
#pragma unroll
  for (int k = 0; k < 8; ++k) {
    int ch = c8 * 8 + k;
    float s = Sacc2[2 * ch], ssum = Sacc2[2 * ch + 1];
    float mean = s * invn;
    float var = ssum * invn - mean * mean;
    float sc = g[ch] / sqrtf(var + EPSV);
    float sh = bt[ch] - mean * sc;
    float v = fmaxf(fmaf(bs2f(a[k]), sc, sh), 0.f) + fmaxf(fmaf(bs2f(b[k]), sc, sh), 0.f)
            + fmaxf(fmaf(bs2f(cc[k]), sc, sh), 0.f) + fmaxf(fmaf(bs2f(d[k]), sc, sh), 0.f);
    res.h[k] = f2b(v * 0.25f);
  }
  *(v8s*)(out + (img * 36 + pp) * 32 + c8 * 8) = res.v;
}

// ---------- conv3 apply: inline bnp3; pool + broadcast to 4 beams ----------
__global__ __launch_bounds__(256) void conv3_apply_k(
    const float* __restrict__ in, const float* __restrict__ Sacc3,
    const float* __restrict__ g, const float* __restrict__ bt,
    float* __restrict__ hs)
{
  int idx = blockIdx.x * 256 + threadIdx.x;  // exactly 2048*128
  int img = idx >> 7, r = idx & 127;
  int c = r >> 2, q = r & 3;
  int py = q >> 1, px = q & 1;
  int p0 = py * 8 + px * 2;
  const float* bp = in + img * 512 + c;
  const float invn = 1.f / (2048.f * 16.f);
  float s = Sacc3[2 * c], ssum = Sacc3[2 * c + 1];
  float mean = s * invn;
  float var = ssum * invn - mean * mean;
  float sc = g[c] / sqrtf(var + EPSV);
  float sh = bt[c] - mean * sc;
  float v = (fmaxf(fmaf(bp[p0 * 32], sc, sh), 0.f)
           + fmaxf(fmaf(bp[(p0 + 1) * 32], sc, sh), 0.f)
           + fmaxf(fmaf(bp[(p0 + 4) * 32], sc, sh), 0.f)
           + fmaxf(fmaf(bp[(p0 + 5) * 32], sc, sh), 0.f)) * 0.25f;
  float* hb = hs + img * 512 + r;
  hb[0] = v; hb[128] = v; hb[256] = v; hb[384] = v;
}

// ---------- fused MoE 3 steps + head, state in wave-private LDS ----------
__global__ __launch_bounds__(256) void moe_fused_k(
    const float* __restrict__ hs, const bf16* __restrict__ Web,
    const float* __restrict__ be, const bf16* __restrict__ Wob,
    const float* __restrict__ bo, const float* __restrict__ sv,
    const int* __restrict__ cnt27, const int* __restrict__ lists,
    float* __restrict__ out)
{
  int t = threadIdx.x, lane = t & 63, wv = t >> 6;
  int m = lane & 15, kg = lane >> 4;
  __shared__ float st[4][16][132];

  int g = blockIdx.x * 4 + wv;
  int sig = -1, tile = 0, cntS = 0, base = 0;
  for (int s = 0; s < 64; ++s) {
    int c = cnt27[s], nt = (c + 15) >> 4;
    if (g >= base && g < base + nt) { sig = s; tile = g - base; cntS = c; }
    base += nt;
  }
  if (sig < 0) return;
  const int* lp = lists + sig * 8192;
  int ra = tile * 16 + m;
  int rowA = lp[ra < cntS ? ra : cntS - 1];

  const float* hrow = hs + rowA * 128 + kg * 32;
#pragma unroll
  for (int q = 0; q < 8; ++q)
    *(float4*)&st[wv][m][kg * 32 + q * 4] = ((const float4*)hrow)[q];

  int es[3] = { sig & 3, (sig >> 2) & 3, sig >> 4 };
#pragma unroll
  for (int stp = 0; stp < 3; ++stp) {
    int e = es[stp];
    if (e == 3) continue;
    const short* wbs = (const short*)(Web + e * 16384);
    v8s afr[4];
#pragma unroll
    for (int kk = 0; kk < 4; ++kk) {
      float4 a0 = *(const float4*)&st[wv][m][kk * 32 + kg * 8];
      float4 a1 = *(const float4*)&st[wv][m][kk * 32 + kg * 8 + 4];
      afr[kk][0] = f2bs(a0.x); afr[kk][1] = f2bs(a0.y);
      afr[kk][2] = f2bs(a0.z); afr[kk][3] = f2bs(a0.w);
      afr[kk][4] = f2bs(a1.x); afr[kk][5] = f2bs(a1.y);
      afr[kk][6] = f2bs(a1.z); afr[kk][7] = f2bs(a1.w);
    }
#pragma unroll
    for (int ob = 0; ob < 8; ++ob) {
      v4f acc = {0.f, 0.f, 0.f, 0.f};
#pragma unroll
      for (int kk = 0; kk < 4; ++kk) {
        v8s bfr;
#pragma unroll
        for (int j = 0; j < 8; ++j)
          bfr[j] = wbs[(kk * 32 + kg * 8 + j) * 128 + ob * 16 + m];
        acc = __builtin_amdgcn_mfma_f32_16x16x32_bf16(afr[kk], bfr, acc, 0, 0, 0);
      }
      float bb = be[e * 128 + ob * 16 + m];
#pragma unroll
      for (int j = 0; j < 4; ++j)
        st[wv][kg * 4 + j][ob * 16 + m] = fmaxf(acc[j] + bb, 0.f);
    }
  }

  float ps = 1.f;
#pragma unroll
  for (int i = 0; i < 12; ++i) ps *= sv[i];
  const short* wos = (const short*)Wob;
  v8s afr[4];
#pragma unroll
  for (int kk = 0; kk < 4; ++kk) {
    float4 a0 = *(const float4*)&st[wv][m][kk * 32 + kg * 8];
    float4 a1 = *(const float4*)&st[wv][m][kk * 32 + kg * 8 + 4];
    afr[kk][0] = f2bs(a0.x); afr[kk][1] = f2bs(a0.y);
    afr[kk][2] = f2bs(a0.z); afr[kk][3] = f2bs(a0.w);
    afr[kk][4] = f2bs(a1.x); afr[kk][5] = f2bs(a1.y);
    afr[kk][6] = f2bs(a1.z); afr[kk][7] = f2bs(a1.w);
  }
  v4f acc = {0.f, 0.f, 0.f, 0.f};
#pragma unroll
  for (int kk = 0; kk < 4; ++kk) {
    v8s bfr;
#pragma unroll
    for (int j = 0; j < 8; ++j)
      bfr[j] = wos[(kk * 32 + kg * 8 + j) * 16 + m];
    acc = __builtin_amdgcn_mfma_f32_16x16x32_bf16(afr[kk], bfr, acc, 0, 0, 0);
  }
  if (m < 10) {
    float bov = bo[m];
#pragma unroll
    for (int j = 0; j < 4; ++j) {
      int idx = tile * 16 + kg * 4 + j;
      if (idx < cntS) out[lp[idx] * 10 + m] = (acc[j] + bov) * ps;
    }
  }
}

extern "C" void kernel_launch(void* const* d_in, const int* in_sizes, int n_in,
                              void* d_out, int out_size, void* d_ws, size_t ws_size,
                              hipStream_t stream)
{
  float* out = (float*)d_out;

  static const int EXP[19] = {2097152, 98304, 12, 288, 32, 9216, 32, 9216, 32,
                              32, 32, 32, 32, 32, 32, 49152, 384, 1280, 10};
  int bad = -1;
  if (n_in != 19) bad = 100;
  else
    for (int i = 0; i < 19; ++i)
      if (in_sizes[i] != EXP[i]) { bad = i; break; }
  if (bad >= 0) {
    fill_k<<<(out_size + 255) / 256, 256, 0, stream>>>(out, 1000.f + 10.f * bad, out_size);
    return;
  }
  const size_t NEED = 75764992;
  if (ws_size < NEED) {
    fill_k<<<(out_size + 255) / 256, 256, 0, stream>>>(
        out, 3000.f + (float)(ws_size >> 20), out_size);
    return;
  }

  const float* x    = (const float*)d_in[0];
  const float* traj = (const float*)d_in[1];
  const float* sv   = (const float*)d_in[2];
  const float* c1w  = (const float*)d_in[3];
  const float* c1b  = (const float*)d_in[4];
  const float* c2w  = (const float*)d_in[5];
  const float* c3w  = (const float*)d_in[7];
  const float* g1   = (const float*)d_in[9];
  const float* bt1  = (const float*)d_in[10];
  const float* g2   = (const float*)d_in[11];
  const float* bt2  = (const float*)d_in[12];
  const float* g3   = (const float*)d_in[13];
  const float* bt3  = (const float*)d_in[14];
  const float* We   = (const float*)d_in[15];
  const float* be   = (const float*)d_in[16];
  const float* Wo   = (const float*)d_in[17];
  const float* bo   = (const float*)d_in[18];

  char* w = (char*)d_ws;
  bf16*  pooled1  = (bf16*)(w + 0);          // NHWC bf16, 29,491,200 B
  bf16*  conv2out = (bf16*)(w + 29491200);   // NHWC bf16, 22,151,168 B
  bf16*  pooled2  = (bf16*)(w + 51642368);   // NHWC bf16, 4,718,592 B
  bf16*  Web      = (bf16*)(w + 56360960);   // 98,304 B
  float* conv3out = (float*)(w + 61079552);  // NHWC f32, 4,194,304 B
  float* hsA      = (float*)(w + 65273856);  // 4,194,304 B
  float* hsB      = (float*)(w + 69468160);  // weight staging only
  float* Macc     = (float*)(w + 73662464);  // 64 f32 (54 used)
  float* Sacc2    = (float*)(w + 73662720);  // 64 f32
  float* Sacc3    = (float*)(w + 73662976);  // 64 f32
  int*   cnt27    = (int*)(w + 73663488);    // 256 B
  bf16*  Wob      = (bf16*)(w + 73663744);   // 4,096 B
  int*   lists    = (int*)(w + 73667840);    // 64*8192*4 = 2,097,152 -> end 75,764,992
  bf16*  w2b      = (bf16*)hsB;
  bf16*  w3b      = w2b + 9216;

  setup_k<<<272, 256, 0, stream>>>(c2w, c3w, We, Wo, w2b, w3b, Web, Wob,
                                   cnt27, Macc, Sacc2, Sacc3);
  front_k<<<544, 256, 0, stream>>>(traj, x, cnt27, lists, Macc);
  conv1_apply_k<<<2048, 256, 0, stream>>>(x, c1w, c1b, g1, bt1, Macc, pooled1);
  conv_mfma_k<15, 13, 169, true><<<2048, 256, 0, stream>>>(pooled1, w2b, conv2out,
                                                           Sacc2, 21632);
  conv2_apply_k<<<1152, 256, 0, stream>>>(conv2out, Sacc2, g2, bt2, pooled2);
  conv_mfma_k<6, 4, 16, false><<<512, 256, 0, stream>>>(pooled2, w3b, conv3out,
                                                        Sacc3, 2048);
  conv3_apply_k<<<1024, 256, 0, stream>>>(conv3out, Sacc3, g3, bt3, hsA);
  moe_fused_k<<<256, 256, 0, stream>>>(hsA, Web, be, Wob, bo, sv, cnt27, lists, out);
}

// Round 14
// 113.042 us; speedup vs baseline: 1.4794x; 1.4794x over previous
//
#include <hip/hip_runtime.h>
#include <hip/hip_bf16.h>

#define EPSV 1e-5f
typedef __hip_bfloat16 bf16;
typedef __attribute__((ext_vector_type(8))) short v8s;
typedef __attribute__((ext_vector_type(4))) float v4f;
__device__ __forceinline__ float b2f(bf16 v) { return __bfloat162float(v); }
__device__ __forceinline__ bf16 f2b(float v) { return __float2bfloat16(v); }
__device__ __forceinline__ float bs2f(short s) {
  return __uint_as_float(((unsigned)(unsigned short)s) << 16);
}
__device__ __forceinline__ short f2bs(float v) {
  bf16 b = __float2bfloat16(v);
  return *(short*)&b;
}

__global__ __launch_bounds__(256) void fill_k(float* __restrict__ out, float val, int n)
{
  int i = blockIdx.x * 256 + threadIdx.x;
  if (i < n) out[i] = val;
}

// ---------- setup: zero slotted accumulators/cnt; pack weights; Web; Wob ----------
__global__ __launch_bounds__(256) void setup_k(
    const float* __restrict__ w2, const float* __restrict__ w3,
    const float* __restrict__ We, const float* __restrict__ Wo,
    bf16* __restrict__ w2b, bf16* __restrict__ w3b,
    bf16* __restrict__ Web, bf16* __restrict__ Wob,
    int* __restrict__ cnt27, float* __restrict__ Macc,
    float* __restrict__ Sacc2, float* __restrict__ Sacc3)
{
  int i = blockIdx.x * 256 + threadIdx.x;
  if (i < 64) cnt27[i] = 0;
  if (i < 512) {                              // 8 slots x 64
    Macc[i] = 0.f;
    Sacc2[i] = 0.f;
    Sacc3[i] = 0.f;
  }
  if (i < 9216) {
    int oc = i / 288, r = i - oc * 288, s = r >> 5, ic = r & 31;  // [oc][s*32+ic]
    w2b[i] = f2b(w2[oc * 288 + ic * 9 + s]);
  } else if (i < 18432) {
    int j = i - 9216;
    int oc = j / 288, r = j - oc * 288, s = r >> 5, ic = r & 31;
    w3b[j] = f2b(w3[oc * 288 + ic * 9 + s]);
  } else if (i < 18432 + 49152) {
    Web[i - 18432] = f2b(We[i - 18432]);
  } else if (i < 18432 + 49152 + 2048) {
    int j = i - 18432 - 49152;               // j = k*16 + o
    int k = j >> 4, o = j & 15;
    Wob[j] = (o < 10) ? f2b(Wo[o * 128 + k]) : f2b(0.f);
  }
}

// ---------- front: blocks 0-31 = signature compaction; 32-543 = conv1 autocorr ----------
__global__ __launch_bounds__(256) void front_k(
    const float* __restrict__ traj, const float* __restrict__ x,
    int* __restrict__ cnt27, int* __restrict__ lists, float* __restrict__ Macc)
{
  int t = threadIdx.x;
  if (blockIdx.x < 32) {
    int row = blockIdx.x * 256 + t;
    __shared__ int lcnt[64], lbase[64];
    if (t < 64) lcnt[t] = 0;
    __syncthreads();
    int e[3];
#pragma unroll
    for (int s = 0; s < 3; ++s) {
      float4 tv = ((const float4*)traj)[s * 8192 + row];
      int ee = 0; float bv = tv.x;
      if (tv.y > bv) { bv = tv.y; ee = 1; }
      if (tv.z > bv) { bv = tv.z; ee = 2; }
      if (tv.w > bv) { bv = tv.w; ee = 3; }
      e[s] = ee;
    }
    int sig = e[0] + 4 * e[1] + 16 * e[2];
    int my = atomicAdd(&lcnt[sig], 1);
    __syncthreads();
    if (t < 64) lbase[t] = atomicAdd(&cnt27[t], lcnt[t]);
    __syncthreads();
    lists[sig * 8192 + lbase[sig] + my] = row;
    return;
  }
  // conv1 autocorrelation: 4 images per block
  int blk = blockIdx.x - 32;
  __shared__ __align__(16) float xs[1024];
  float M[45], S[9];
#pragma unroll
  for (int k = 0; k < 45; ++k) M[k] = 0.f;
#pragma unroll
  for (int k = 0; k < 9; ++k) S[k] = 0.f;
  for (int im = 0; im < 4; ++im) {
    int img = blk * 4 + im;
    ((float4*)xs)[t] = ((const float4*)(x + img * 1024))[t];
    __syncthreads();
    for (int p = t; p < 900; p += 256) {
      int y = p / 30, xx = p - y * 30;
      const float* r0 = xs + y * 32 + xx;
      float v[9];
      v[0] = r0[0];  v[1] = r0[1];  v[2] = r0[2];
      v[3] = r0[32]; v[4] = r0[33]; v[5] = r0[34];
      v[6] = r0[64]; v[7] = r0[65]; v[8] = r0[66];
      int idx = 0;
#pragma unroll
      for (int i = 0; i < 9; ++i) {
        S[i] += v[i];
#pragma unroll
        for (int j = i; j < 9; ++j) M[idx++] = fmaf(v[i], v[j], M[idx]);
      }
    }
    __syncthreads();
  }
  float a[54];
#pragma unroll
  for (int k = 0; k < 45; ++k) a[k] = M[k];
#pragma unroll
  for (int k = 0; k < 9; ++k) a[45 + k] = S[k];
#pragma unroll
  for (int k = 0; k < 54; ++k) {
#pragma unroll
    for (int off = 32; off; off >>= 1) a[k] += __shfl_down(a[k], off, 64);
  }
  __shared__ float red[4][54];
  int wv = t >> 6, lane = t & 63;
  if (lane == 0) {
#pragma unroll
    for (int k = 0; k < 54; ++k) red[wv][k] = a[k];
  }
  __syncthreads();
  if (t < 54)
    atomicAdd(&Macc[(blk & 7) * 64 + t], red[0][t] + red[1][t] + red[2][t] + red[3][t]);
}

// ---------- conv1 apply: inline BN params from slotted autocorr sums ----------
__global__ __launch_bounds__(256) void conv1_apply_k(
    const float* __restrict__ x, const float* __restrict__ w1,
    const float* __restrict__ b1, const float* __restrict__ g,
    const float* __restrict__ bt, const float* __restrict__ Macc,
    bf16* __restrict__ pooled1)
{
  int img = blockIdx.x, t = threadIdx.x;
  __shared__ __align__(16) float xs[1024];
  __shared__ float Ms[54];
  ((float4*)xs)[t] = ((const float4*)(x + img * 1024))[t];
  if (t < 54) {
    float s = 0.f;
#pragma unroll
    for (int sl = 0; sl < 8; ++sl) s += Macc[sl * 64 + t];
    Ms[t] = s;
  }
  __syncthreads();
  int c = t & 31;
  float w[9];
#pragma unroll
  for (int j = 0; j < 9; ++j) w[j] = w1[c * 9 + j];
  float bias = b1[c];
  float wS = 0.f;
#pragma unroll
  for (int i = 0; i < 9; ++i) wS = fmaf(w[i], Ms[45 + i], wS);
  float wMw = 0.f;
  {
    int idx = 0;
#pragma unroll
    for (int i = 0; i < 9; ++i)
#pragma unroll
      for (int j = i; j < 9; ++j) {
        float coef = (i == j) ? 1.f : 2.f;
        wMw = fmaf(coef * w[i] * w[j], Ms[idx], wMw);
        ++idx;
      }
  }
  const float Np = 2048.f * 900.f;
  float mean = (wS + Np * bias) / Np;
  float sumsq = wMw + 2.f * bias * wS + Np * bias * bias;
  float var = sumsq / Np - mean * mean;
  float sc = g[c] / sqrtf(var + EPSV);
  float sh = bt[c] - mean * sc;

  bf16* outp = pooled1 + img * 7200;
  for (int idx = t; idx < 7200; idx += 256) {
    int pp = idx >> 5;
    int py = pp / 15, px = pp - py * 15;
    int y0 = 2 * py, x0 = 2 * px;
    float rv[4][4];
#pragma unroll
    for (int rr = 0; rr < 4; ++rr) {
      float2 lo = *(const float2*)(xs + (y0 + rr) * 32 + x0);
      float2 hi = *(const float2*)(xs + (y0 + rr) * 32 + x0 + 2);
      rv[rr][0] = lo.x; rv[rr][1] = lo.y; rv[rr][2] = hi.x; rv[rr][3] = hi.y;
    }
    float r = 0.f;
#pragma unroll
    for (int i = 0; i < 2; ++i)
#pragma unroll
      for (int j = 0; j < 2; ++j) {
        float v = bias;
        v = fmaf(rv[i][j],     w[0], v); v = fmaf(rv[i][j + 1],     w[1], v); v = fmaf(rv[i][j + 2],     w[2], v);
        v = fmaf(rv[i + 1][j], w[3], v); v = fmaf(rv[i + 1][j + 1], w[4], v); v = fmaf(rv[i + 1][j + 2], w[5], v);
        v = fmaf(rv[i + 2][j], w[6], v); v = fmaf(rv[i + 2][j + 1], w[7], v); v = fmaf(rv[i + 2][j + 2], w[8], v);
        r += fmaxf(fmaf(v, sc, sh), 0.f);
      }
    outp[idx] = f2b(r * 0.25f);
  }
}

// ---------- implicit-GEMM conv via MFMA; launch_bounds(256,2) => no VGPR spill ----------
template <int IN_W, int OUT_W, int OUT_PIX, bool OUT_BF16>
__global__ __launch_bounds__(256, 2) void conv_mfma_k(
    const bf16* __restrict__ in, const bf16* __restrict__ wb,
    void* __restrict__ outv, float* __restrict__ sacc, int ntiles)
{
  constexpr int IN_PIX = IN_W * IN_W;
  int t = threadIdx.x, lane = t & 63;
  int m = lane & 15, kg = lane >> 4;
  const short* wbs = (const short*)wb;
  v8s bfr[9][2];
#pragma unroll
  for (int s = 0; s < 9; ++s)
#pragma unroll
    for (int ob = 0; ob < 2; ++ob)
      bfr[s][ob] = *(const v8s*)(wbs + (ob * 16 + m) * 288 + s * 32 + kg * 8);

  float rs0 = 0.f, rss0 = 0.f, rs1 = 0.f, rss1 = 0.f;
  int gwave = blockIdx.x * 4 + (t >> 6);
  int nw = gridDim.x * 4;
  for (int tile = gwave; tile < ntiles; tile += nw) {
    unsigned p = tile * 16 + m;
    unsigned img = p / OUT_PIX, pix = p - img * OUT_PIX;
    unsigned y = pix / OUT_W, x = pix - y * OUT_W;
    const bf16* ap = in + img * (IN_PIX * 32) + (y * IN_W + x) * 32 + kg * 8;
    v4f acc0 = {0.f, 0.f, 0.f, 0.f}, acc1 = {0.f, 0.f, 0.f, 0.f};
#pragma unroll
    for (int ky = 0; ky < 3; ++ky)
#pragma unroll
      for (int kx = 0; kx < 3; ++kx) {
        v8s a = *(const v8s*)(ap + (ky * IN_W + kx) * 32);
        acc0 = __builtin_amdgcn_mfma_f32_16x16x32_bf16(a, bfr[ky * 3 + kx][0], acc0, 0, 0, 0);
        acc1 = __builtin_amdgcn_mfma_f32_16x16x32_bf16(a, bfr[ky * 3 + kx][1], acc1, 0, 0, 0);
      }
    // C rows are globally pixel-contiguous: out index = pr*32 + ch
#pragma unroll
    for (int j = 0; j < 4; ++j) {
      rs0 += acc0[j]; rss0 = fmaf(acc0[j], acc0[j], rss0);
      rs1 += acc1[j]; rss1 = fmaf(acc1[j], acc1[j], rss1);
      unsigned pr = tile * 16 + kg * 4 + j;
      unsigned base = pr * 32;
      if (OUT_BF16) {
        bf16* o = (bf16*)outv;
        o[base + m] = f2b(acc0[j]);
        o[base + 16 + m] = f2b(acc1[j]);
      } else {
        float* o = (float*)outv;
        o[base + m] = acc0[j];
        o[base + 16 + m] = acc1[j];
      }
    }
  }
  rs0 += __shfl_xor(rs0, 16, 64);  rss0 += __shfl_xor(rss0, 16, 64);
  rs0 += __shfl_xor(rs0, 32, 64);  rss0 += __shfl_xor(rss0, 32, 64);
  rs1 += __shfl_xor(rs1, 16, 64);  rss1 += __shfl_xor(rss1, 16, 64);
  rs1 += __shfl_xor(rs1, 32, 64);  rss1 += __shfl_xor(rss1, 32, 64);
  __shared__ float red[4][32][2];
  int wv = t >> 6;
  if (lane < 16) {
    red[wv][lane][0] = rs0;      red[wv][lane][1] = rss0;
    red[wv][16 + lane][0] = rs1; red[wv][16 + lane][1] = rss1;
  }
  __syncthreads();
  if (t < 64) {
    int cc = t >> 1, j = t & 1;
    atomicAdd(&sacc[(blockIdx.x & 7) * 64 + t],
              red[0][cc][j] + red[1][cc][j] + red[2][cc][j] + red[3][cc][j]);
  }
}

// ---------- conv2 apply: inline bnp2 from slotted Sacc2; BN+ReLU+pool -> NHWC bf16 ----------
__global__ __launch_bounds__(256) void conv2_apply_k(
    const bf16* __restrict__ in, const float* __restrict__ Sacc2,
    const float* __restrict__ g, const float* __restrict__ bt,
    bf16* __restrict__ out)
{
  int idx = blockIdx.x * 256 + threadIdx.x;  // exactly 2048*36*4
  int img = idx / 144, r = idx - img * 144;
  int pp = r >> 2, c8 = r & 3;
  int py = pp / 6, px = pp - py * 6;
  int ip0 = (2 * py) * 13 + 2 * px;
  const bf16* bp = in + (img * 169 + ip0) * 32 + c8 * 8;
  v8s a = *(const v8s*)bp;
  v8s b = *(const v8s*)(bp + 32);
  v8s cc = *(const v8s*)(bp + 13 * 32);
  v8s d = *(const v8s*)(bp + 14 * 32);
  const float invn = 1.f / (2048.f * 169.f);
  union { v8s v; short s[8]; bf16 h[8]; } res;
#pragma unroll
  for (int k = 0; k < 8; ++k) {
    int ch = c8 * 8 + k;
    float s = 0.f, ssum = 0.f;
#pragma unroll
    for (int sl = 0; sl < 8; ++sl) {
      s += Sacc2[sl * 64 + 2 * ch];
      ssum += Sacc2[sl * 64 + 2 * ch + 1];
    }
    float mean = s * invn;
    float var = ssum * invn - mean * mean;
    float sc = g[ch] / sqrtf(var + EPSV);
    float sh = bt[ch] - mean * sc;
    float v = fmaxf(fmaf(bs2f(a[k]), sc, sh), 0.f) + fmaxf(fmaf(bs2f(b[k]), sc, sh), 0.f)
            + fmaxf(fmaf(bs2f(cc[k]), sc, sh), 0.f) + fmaxf(fmaf(bs2f(d[k]), sc, sh), 0.f);
    res.h[k] = f2b(v * 0.25f);
  }
  *(v8s*)(out + (img * 36 + pp) * 32 + c8 * 8) = res.v;
}

// ---------- conv3 apply: inline bnp3 from slotted Sacc3; pool + broadcast ----------
__global__ __launch_bounds__(256) void conv3_apply_k(
    const float* __restrict__ in, const float* __restrict__ Sacc3,
    const float* __restrict__ g, const float* __restrict__ bt,
    float* __restrict__ hs)
{
  int idx = blockIdx.x * 256 + threadIdx.x;  // exactly 2048*128
  int img = idx >> 7, r = idx & 127;
  int c = r >> 2, q = r & 3;
  int py = q >> 1, px = q & 1;
  int p0 = py * 8 + px * 2;
  const float* bp = in + img * 512 + c;
  const float invn = 1.f / (2048.f * 16.f);
  float s = 0.f, ssum = 0.f;
#pragma unroll
  for (int sl = 0; sl < 8; ++sl) {
    s += Sacc3[sl * 64 + 2 * c];
    ssum += Sacc3[sl * 64 + 2 * c + 1];
  }
  float mean = s * invn;
  float var = ssum * invn - mean * mean;
  float sc = g[c] / sqrtf(var + EPSV);
  float sh = bt[c] - mean * sc;
  float v = (fmaxf(fmaf(bp[p0 * 32], sc, sh), 0.f)
           + fmaxf(fmaf(bp[(p0 + 1) * 32], sc, sh), 0.f)
           + fmaxf(fmaf(bp[(p0 + 4) * 32], sc, sh), 0.f)
           + fmaxf(fmaf(bp[(p0 + 5) * 32], sc, sh), 0.f)) * 0.25f;
  float* hb = hs + img * 512 + r;
  hb[0] = v; hb[128] = v; hb[256] = v; hb[384] = v;
}

// ---------- fused MoE 3 steps + head, state in wave-private LDS ----------
__global__ __launch_bounds__(256) void moe_fused_k(
    const float* __restrict__ hs, const bf16* __restrict__ Web,
    const float* __restrict__ be, const bf16* __restrict__ Wob,
    const float* __restrict__ bo, const float* __restrict__ sv,
    const int* __restrict__ cnt27, const int* __restrict__ lists,
    float* __restrict__ out)
{
  int t = threadIdx.x, lane = t & 63, wv = t >> 6;
  int m = lane & 15, kg = lane >> 4;
  __shared__ float st[4][16][132];

  int g = blockIdx.x * 4 + wv;
  int sig = -1, tile = 0, cntS = 0, base = 0;
  for (int s = 0; s < 64; ++s) {
    int c = cnt27[s], nt = (c + 15) >> 4;
    if (g >= base && g < base + nt) { sig = s; tile = g - base; cntS = c; }
    base += nt;
  }
  if (sig < 0) return;
  const int* lp = lists + sig * 8192;
  int ra = tile * 16 + m;
  int rowA = lp[ra < cntS ? ra : cntS - 1];

  const float* hrow = hs + rowA * 128 + kg * 32;
#pragma unroll
  for (int q = 0; q < 8; ++q)
    *(float4*)&st[wv][m][kg * 32 + q * 4] = ((const float4*)hrow)[q];

  int es[3] = { sig & 3, (sig >> 2) & 3, sig >> 4 };
#pragma unroll
  for (int stp = 0; stp < 3; ++stp) {
    int e = es[stp];
    if (e == 3) continue;
    const short* wbs = (const short*)(Web + e * 16384);
    v8s afr[4];
#pragma unroll
    for (int kk = 0; kk < 4; ++kk) {
      float4 a0 = *(const float4*)&st[wv][m][kk * 32 + kg * 8];
      float4 a1 = *(const float4*)&st[wv][m][kk * 32 + kg * 8 + 4];
      afr[kk][0] = f2bs(a0.x); afr[kk][1] = f2bs(a0.y);
      afr[kk][2] = f2bs(a0.z); afr[kk][3] = f2bs(a0.w);
      afr[kk][4] = f2bs(a1.x); afr[kk][5] = f2bs(a1.y);
      afr[kk][6] = f2bs(a1.z); afr[kk][7] = f2bs(a1.w);
    }
#pragma unroll
    for (int ob = 0; ob < 8; ++ob) {
      v4f acc = {0.f, 0.f, 0.f, 0.f};
#pragma unroll
      for (int kk = 0; kk < 4; ++kk) {
        v8s bfr;
#pragma unroll
        for (int j = 0; j < 8; ++j)
          bfr[j] = wbs[(kk * 32 + kg * 8 + j) * 128 + ob * 16 + m];
        acc = __builtin_amdgcn_mfma_f32_16x16x32_bf16(afr[kk], bfr, acc, 0, 0, 0);
      }
      float bb = be[e * 128 + ob * 16 + m];
#pragma unroll
      for (int j = 0; j < 4; ++j)
        st[wv][kg * 4 + j][ob * 16 + m] = fmaxf(acc[j] + bb, 0.f);
    }
  }

  float ps = 1.f;
#pragma unroll
  for (int i = 0; i < 12; ++i) ps *= sv[i];
  const short* wos = (const short*)Wob;
  v8s afr[4];
#pragma unroll
  for (int kk = 0; kk < 4; ++kk) {
    float4 a0 = *(const float4*)&st[wv][m][kk * 32 + kg * 8];
    float4 a1 = *(const float4*)&st[wv][m][kk * 32 + kg * 8 + 4];
    afr[kk][0] = f2bs(a0.x); afr[kk][1] = f2bs(a0.y);
    afr[kk][2] = f2bs(a0.z); afr[kk][3] = f2bs(a0.w);
    afr[kk][4] = f2bs(a1.x); afr[kk][5] = f2bs(a1.y);
    afr[kk][6] = f2bs(a1.z); afr[kk][7] = f2bs(a1.w);
  }
  v4f acc = {0.f, 0.f, 0.f, 0.f};
#pragma unroll
  for (int kk = 0; kk < 4; ++kk) {
    v8s bfr;
#pragma unroll
    for (int j = 0; j < 8; ++j)
      bfr[j] = wos[(kk * 32 + kg * 8 + j) * 16 + m];
    acc = __builtin_amdgcn_mfma_f32_16x16x32_bf16(afr[kk], bfr, acc, 0, 0, 0);
  }
  if (m < 10) {
    float bov = bo[m];
#pragma unroll
    for (int j = 0; j < 4; ++j) {
      int idx = tile * 16 + kg * 4 + j;
      if (idx < cntS) out[lp[idx] * 10 + m] = (acc[j] + bov) * ps;
    }
  }
}

extern "C" void kernel_launch(void* const* d_in, const int* in_sizes, int n_in,
                              void* d_out, int out_size, void* d_ws, size_t ws_size,
                              hipStream_t stream)
{
  float* out = (float*)d_out;

  static const int EXP[19] = {2097152, 98304, 12, 288, 32, 9216, 32, 9216, 32,
                              32, 32, 32, 32, 32, 32, 49152, 384, 1280, 10};
  int bad = -1;
  if (n_in != 19) bad = 100;
  else
    for (int i = 0; i < 19; ++i)
      if (in_sizes[i] != EXP[i]) { bad = i; break; }
  if (bad >= 0) {
    fill_k<<<(out_size + 255) / 256, 256, 0, stream>>>(out, 1000.f + 10.f * bad, out_size);
    return;
  }
  const size_t NEED = 75771904;
  if (ws_size < NEED) {
    fill_k<<<(out_size + 255) / 256, 256, 0, stream>>>(
        out, 3000.f + (float)(ws_size >> 20), out_size);
    return;
  }

  const float* x    = (const float*)d_in[0];
  const float* traj = (const float*)d_in[1];
  const float* sv   = (const float*)d_in[2];
  const float* c1w  = (const float*)d_in[3];
  const float* c1b  = (const float*)d_in[4];
  const float* c2w  = (const float*)d_in[5];
  const float* c3w  = (const float*)d_in[7];
  const float* g1   = (const float*)d_in[9];
  const float* bt1  = (const float*)d_in[10];
  const float* g2   = (const float*)d_in[11];
  const float* bt2  = (const float*)d_in[12];
  const float* g3   = (const float*)d_in[13];
  const float* bt3  = (const float*)d_in[14];
  const float* We   = (const float*)d_in[15];
  const float* be   = (const float*)d_in[16];
  const float* Wo   = (const float*)d_in[17];
  const float* bo   = (const float*)d_in[18];

  char* w = (char*)d_ws;
  bf16*  pooled1  = (bf16*)(w + 0);          // NHWC bf16, 29,491,200 B
  bf16*  conv2out = (bf16*)(w + 29491200);   // NHWC bf16, 22,151,168 B
  bf16*  pooled2  = (bf16*)(w + 51642368);   // NHWC bf16, 4,718,592 B
  bf16*  Web      = (bf16*)(w + 56360960);   // 98,304 B
  float* conv3out = (float*)(w + 61079552);  // NHWC f32, 4,194,304 B
  float* hsA      = (float*)(w + 65273856);  // 4,194,304 B
  float* hsB      = (float*)(w + 69468160);  // weight staging only
  float* Macc     = (float*)(w + 73662464);  // 8 slots x 64 f32 = 2048 B
  float* Sacc2    = (float*)(w + 73664512);  // 2048 B
  float* Sacc3    = (float*)(w + 73666560);  // 2048 B
  int*   cnt27    = (int*)(w + 73668608);    // 256 B
  bf16*  Wob      = (bf16*)(w + 73670656);   // 4,096 B
  int*   lists    = (int*)(w + 73674752);    // 64*8192*4 = 2,097,152 -> end 75,771,904
  bf16*  w2b      = (bf16*)hsB;
  bf16*  w3b      = w2b + 9216;

  setup_k<<<272, 256, 0, stream>>>(c2w, c3w, We, Wo, w2b, w3b, Web, Wob,
                                   cnt27, Macc, Sacc2, Sacc3);
  front_k<<<544, 256, 0, stream>>>(traj, x, cnt27, lists, Macc);
  conv1_apply_k<<<2048, 256, 0, stream>>>(x, c1w, c1b, g1, bt1, Macc, pooled1);
  conv_mfma_k<15, 13, 169, true><<<1024, 256, 0, stream>>>(pooled1, w2b, conv2out,
                                                           Sacc2, 21632);
  conv2_apply_k<<<1152, 256, 0, stream>>>(conv2out, Sacc2, g2, bt2, pooled2);
  conv_mfma_k<6, 4, 16, false><<<256, 256, 0, stream>>>(pooled2, w3b, conv3out,
                                                        Sacc3, 2048);
  conv3_apply_k<<<1024, 256, 0, stream>>>(conv3out, Sacc3, g3, bt3, hsA);
  moe_fused_k<<<256, 256, 0, stream>>>(hsA, Web, be, Wob, bo, sv, cnt27, lists, out);
}

// Round 15
// 106.174 us; speedup vs baseline: 1.5751x; 1.0647x over previous
//
#include <hip/hip_runtime.h>
#include <hip/hip_bf16.h>

#define EPSV 1e-5f
typedef __hip_bfloat16 bf16;
typedef __attribute__((ext_vector_type(8))) short v8s;
typedef __attribute__((ext_vector_type(4))) float v4f;
__device__ __forceinline__ float b2f(bf16 v) { return __bfloat162float(v); }
__device__ __forceinline__ bf16 f2b(float v) { return __float2bfloat16(v); }
__device__ __forceinline__ float bs2f(short s) {
  return __uint_as_float(((unsigned)(unsigned short)s) << 16);
}
__device__ __forceinline__ short f2bs(float v) {
  bf16 b = __float2bfloat16(v);
  return *(short*)&b;
}

__global__ __launch_bounds__(256) void fill_k(float* __restrict__ out, float val, int n)
{
  int i = blockIdx.x * 256 + threadIdx.x;
  if (i < n) out[i] = val;
}

// ---------- setup: zero slotted accumulators/cnt; pack weights; Web; Wob ----------
__global__ __launch_bounds__(256) void setup_k(
    const float* __restrict__ w2, const float* __restrict__ w3,
    const float* __restrict__ We, const float* __restrict__ Wo,
    bf16* __restrict__ w2b, bf16* __restrict__ w3b,
    bf16* __restrict__ Web, bf16* __restrict__ Wob,
    int* __restrict__ cnt27, float* __restrict__ Macc,
    float* __restrict__ Sacc2, float* __restrict__ Sacc3)
{
  int i = blockIdx.x * 256 + threadIdx.x;
  if (i < 64) cnt27[i] = 0;
  if (i < 512) {                              // 8 slots x 64
    Macc[i] = 0.f;
    Sacc2[i] = 0.f;
    Sacc3[i] = 0.f;
  }
  if (i < 9216) {
    int oc = i / 288, r = i - oc * 288, s = r >> 5, ic = r & 31;  // [oc][s*32+ic]
    w2b[i] = f2b(w2[oc * 288 + ic * 9 + s]);
  } else if (i < 18432) {
    int j = i - 9216;
    int oc = j / 288, r = j - oc * 288, s = r >> 5, ic = r & 31;
    w3b[j] = f2b(w3[oc * 288 + ic * 9 + s]);
  } else if (i < 18432 + 49152) {
    Web[i - 18432] = f2b(We[i - 18432]);
  } else if (i < 18432 + 49152 + 2048) {
    int j = i - 18432 - 49152;               // j = k*16 + o
    int k = j >> 4, o = j & 15;
    Wob[j] = (o < 10) ? f2b(Wo[o * 128 + k]) : f2b(0.f);
  }
}

// ---------- front: blocks 0-31 = signature compaction; 32-543 = conv1 autocorr ----------
__global__ __launch_bounds__(256) void front_k(
    const float* __restrict__ traj, const float* __restrict__ x,
    int* __restrict__ cnt27, int* __restrict__ lists, float* __restrict__ Macc)
{
  int t = threadIdx.x;
  if (blockIdx.x < 32) {
    int row = blockIdx.x * 256 + t;
    __shared__ int lcnt[64], lbase[64];
    if (t < 64) lcnt[t] = 0;
    __syncthreads();
    int e[3];
#pragma unroll
    for (int s = 0; s < 3; ++s) {
      float4 tv = ((const float4*)traj)[s * 8192 + row];
      int ee = 0; float bv = tv.x;
      if (tv.y > bv) { bv = tv.y; ee = 1; }
      if (tv.z > bv) { bv = tv.z; ee = 2; }
      if (tv.w > bv) { bv = tv.w; ee = 3; }
      e[s] = ee;
    }
    int sig = e[0] + 4 * e[1] + 16 * e[2];
    int my = atomicAdd(&lcnt[sig], 1);
    __syncthreads();
    if (t < 64) lbase[t] = atomicAdd(&cnt27[t], lcnt[t]);
    __syncthreads();
    lists[sig * 8192 + lbase[sig] + my] = row;
    return;
  }
  // conv1 autocorrelation: 4 images per block
  int blk = blockIdx.x - 32;
  __shared__ __align__(16) float xs[1024];
  float M[45], S[9];
#pragma unroll
  for (int k = 0; k < 45; ++k) M[k] = 0.f;
#pragma unroll
  for (int k = 0; k < 9; ++k) S[k] = 0.f;
  for (int im = 0; im < 4; ++im) {
    int img = blk * 4 + im;
    ((float4*)xs)[t] = ((const float4*)(x + img * 1024))[t];
    __syncthreads();
    for (int p = t; p < 900; p += 256) {
      int y = p / 30, xx = p - y * 30;
      const float* r0 = xs + y * 32 + xx;
      float v[9];
      v[0] = r0[0];  v[1] = r0[1];  v[2] = r0[2];
      v[3] = r0[32]; v[4] = r0[33]; v[5] = r0[34];
      v[6] = r0[64]; v[7] = r0[65]; v[8] = r0[66];
      int idx = 0;
#pragma unroll
      for (int i = 0; i < 9; ++i) {
        S[i] += v[i];
#pragma unroll
        for (int j = i; j < 9; ++j) M[idx++] = fmaf(v[i], v[j], M[idx]);
      }
    }
    __syncthreads();
  }
  float a[54];
#pragma unroll
  for (int k = 0; k < 45; ++k) a[k] = M[k];
#pragma unroll
  for (int k = 0; k < 9; ++k) a[45 + k] = S[k];
#pragma unroll
  for (int k = 0; k < 54; ++k) {
#pragma unroll
    for (int off = 32; off; off >>= 1) a[k] += __shfl_down(a[k], off, 64);
  }
  __shared__ float red[4][54];
  int wv = t >> 6, lane = t & 63;
  if (lane == 0) {
#pragma unroll
    for (int k = 0; k < 54; ++k) red[wv][k] = a[k];
  }
  __syncthreads();
  if (t < 54)
    atomicAdd(&Macc[(blk & 7) * 64 + t], red[0][t] + red[1][t] + red[2][t] + red[3][t]);
}

// ---------- conv1 apply v2: 512 thr = (ch, row); sliding 2-col window; BN in LDS ----------
__global__ __launch_bounds__(512) void conv1_apply_k(
    const float* __restrict__ x, const float* __restrict__ w1,
    const float* __restrict__ b1, const float* __restrict__ g,
    const float* __restrict__ bt, const float* __restrict__ Macc,
    bf16* __restrict__ pooled1)
{
  int img = blockIdx.x, t = threadIdx.x;
  __shared__ __align__(16) float xs[1024];
  __shared__ float Ms[54], scs[32], shs[32];
  if (t < 256) ((float4*)xs)[t] = ((const float4*)(x + img * 1024))[t];
  if (t >= 256 && t < 310) {
    int k = t - 256;
    float s = 0.f;
#pragma unroll
    for (int sl = 0; sl < 8; ++sl) s += Macc[sl * 64 + k];
    Ms[k] = s;
  }
  __syncthreads();
  if (t < 32) {
    float w[9];
#pragma unroll
    for (int j = 0; j < 9; ++j) w[j] = w1[t * 9 + j];
    float bias = b1[t];
    float wS = 0.f;
#pragma unroll
    for (int i = 0; i < 9; ++i) wS = fmaf(w[i], Ms[45 + i], wS);
    float wMw = 0.f;
    int idx = 0;
#pragma unroll
    for (int i = 0; i < 9; ++i)
#pragma unroll
      for (int j = i; j < 9; ++j) {
        float coef = (i == j) ? 1.f : 2.f;
        wMw = fmaf(coef * w[i] * w[j], Ms[idx], wMw);
        ++idx;
      }
    const float Np = 2048.f * 900.f;
    float mean = (wS + Np * bias) / Np;
    float sumsq = wMw + 2.f * bias * wS + Np * bias * bias;
    float var = sumsq / Np - mean * mean;
    float sc = g[t] / sqrtf(var + EPSV);
    scs[t] = sc;
    shs[t] = bt[t] - mean * sc;
  }
  __syncthreads();
  int ch = t & 31, pg = t >> 5;              // pg = output row, 0..15 (15 used)
  if (pg >= 15) return;
  float w[9];
#pragma unroll
  for (int j = 0; j < 9; ++j) w[j] = w1[ch * 9 + j];
  float bias = b1[ch], sc = scs[ch], sh = shs[ch];
  const float* rp = xs + 2 * pg * 32;
  float a0 = rp[0], a1 = rp[32], a2 = rp[64], a3 = rp[96];
  float b0 = rp[1], b1v = rp[33], b2 = rp[65], b3 = rp[97];
  bf16* orow = pooled1 + img * 7200 + pg * 15 * 32 + ch;
#pragma unroll
  for (int px = 0; px < 15; ++px) {
    int xb = 2 * px;
    float e0 = rp[xb + 2], e1 = rp[xb + 34], e2 = rp[xb + 66], e3 = rp[xb + 98];
    float f0 = rp[xb + 3], f1 = rp[xb + 35], f2 = rp[xb + 67], f3 = rp[xb + 99];
    float v00 = bias, v01 = bias, v10 = bias, v11 = bias;
    v00 = fmaf(a0, w[0], v00); v00 = fmaf(b0, w[1], v00); v00 = fmaf(e0, w[2], v00);
    v00 = fmaf(a1, w[3], v00); v00 = fmaf(b1v, w[4], v00); v00 = fmaf(e1, w[5], v00);
    v00 = fmaf(a2, w[6], v00); v00 = fmaf(b2, w[7], v00); v00 = fmaf(e2, w[8], v00);
    v01 = fmaf(b0, w[0], v01); v01 = fmaf(e0, w[1], v01); v01 = fmaf(f0, w[2], v01);
    v01 = fmaf(b1v, w[3], v01); v01 = fmaf(e1, w[4], v01); v01 = fmaf(f1, w[5], v01);
    v01 = fmaf(b2, w[6], v01); v01 = fmaf(e2, w[7], v01); v01 = fmaf(f2, w[8], v01);
    v10 = fmaf(a1, w[0], v10); v10 = fmaf(b1v, w[1], v10); v10 = fmaf(e1, w[2], v10);
    v10 = fmaf(a2, w[3], v10); v10 = fmaf(b2, w[4], v10); v10 = fmaf(e2, w[5], v10);
    v10 = fmaf(a3, w[6], v10); v10 = fmaf(b3, w[7], v10); v10 = fmaf(e3, w[8], v10);
    v11 = fmaf(b1v, w[0], v11); v11 = fmaf(e1, w[1], v11); v11 = fmaf(f1, w[2], v11);
    v11 = fmaf(b2, w[3], v11); v11 = fmaf(e2, w[4], v11); v11 = fmaf(f2, w[5], v11);
    v11 = fmaf(b3, w[6], v11); v11 = fmaf(e3, w[7], v11); v11 = fmaf(f3, w[8], v11);
    float r = fmaxf(fmaf(v00, sc, sh), 0.f) + fmaxf(fmaf(v01, sc, sh), 0.f)
            + fmaxf(fmaf(v10, sc, sh), 0.f) + fmaxf(fmaf(v11, sc, sh), 0.f);
    orow[px * 32] = f2b(r * 0.25f);
    a0 = e0; a1 = e1; a2 = e2; a3 = e3;
    b0 = f0; b1v = f1; b2 = f2; b3 = f3;
  }
}

// ---------- implicit-GEMM conv via MFMA; launch_bounds(256,2) => no VGPR spill ----------
template <int IN_W, int OUT_W, int OUT_PIX, bool OUT_BF16>
__global__ __launch_bounds__(256, 2) void conv_mfma_k(
    const bf16* __restrict__ in, const bf16* __restrict__ wb,
    void* __restrict__ outv, float* __restrict__ sacc, int ntiles)
{
  constexpr int IN_PIX = IN_W * IN_W;
  int t = threadIdx.x, lane = t & 63;
  int m = lane & 15, kg = lane >> 4;
  const short* wbs = (const short*)wb;
  v8s bfr[9][2];
#pragma unroll
  for (int s = 0; s < 9; ++s)
#pragma unroll
    for (int ob = 0; ob < 2; ++ob)
      bfr[s][ob] = *(const v8s*)(wbs + (ob * 16 + m) * 288 + s * 32 + kg * 8);

  float rs0 = 0.f, rss0 = 0.f, rs1 = 0.f, rss1 = 0.f;
  int gwave = blockIdx.x * 4 + (t >> 6);
  int nw = gridDim.x * 4;
  for (int tile = gwave; tile < ntiles; tile += nw) {
    unsigned p = tile * 16 + m;
    unsigned img = p / OUT_PIX, pix = p - img * OUT_PIX;
    unsigned y = pix / OUT_W, x = pix - y * OUT_W;
    const bf16* ap = in + img * (IN_PIX * 32) + (y * IN_W + x) * 32 + kg * 8;
    v4f acc0 = {0.f, 0.f, 0.f, 0.f}, acc1 = {0.f, 0.f, 0.f, 0.f};
#pragma unroll
    for (int ky = 0; ky < 3; ++ky)
#pragma unroll
      for (int kx = 0; kx < 3; ++kx) {
        v8s a = *(const v8s*)(ap + (ky * IN_W + kx) * 32);
        acc0 = __builtin_amdgcn_mfma_f32_16x16x32_bf16(a, bfr[ky * 3 + kx][0], acc0, 0, 0, 0);
        acc1 = __builtin_amdgcn_mfma_f32_16x16x32_bf16(a, bfr[ky * 3 + kx][1], acc1, 0, 0, 0);
      }
#pragma unroll
    for (int j = 0; j < 4; ++j) {
      rs0 += acc0[j]; rss0 = fmaf(acc0[j], acc0[j], rss0);
      rs1 += acc1[j]; rss1 = fmaf(acc1[j], acc1[j], rss1);
      unsigned pr = tile * 16 + kg * 4 + j;
      unsigned base = pr * 32;
      if (OUT_BF16) {
        bf16* o = (bf16*)outv;
        o[base + m] = f2b(acc0[j]);
        o[base + 16 + m] = f2b(acc1[j]);
      } else {
        float* o = (float*)outv;
        o[base + m] = acc0[j];
        o[base + 16 + m] = acc1[j];
      }
    }
  }
  rs0 += __shfl_xor(rs0, 16, 64);  rss0 += __shfl_xor(rss0, 16, 64);
  rs0 += __shfl_xor(rs0, 32, 64);  rss0 += __shfl_xor(rss0, 32, 64);
  rs1 += __shfl_xor(rs1, 16, 64);  rss1 += __shfl_xor(rss1, 16, 64);
  rs1 += __shfl_xor(rs1, 32, 64);  rss1 += __shfl_xor(rss1, 32, 64);
  __shared__ float red[4][32][2];
  int wv = t >> 6;
  if (lane < 16) {
    red[wv][lane][0] = rs0;      red[wv][lane][1] = rss0;
    red[wv][16 + lane][0] = rs1; red[wv][16 + lane][1] = rss1;
  }
  __syncthreads();
  if (t < 64) {
    int cc = t >> 1, j = t & 1;
    atomicAdd(&sacc[(blockIdx.x & 7) * 64 + t],
              red[0][cc][j] + red[1][cc][j] + red[2][cc][j] + red[3][cc][j]);
  }
}

// ---------- conv2 apply: LDS-shared BN params; BN+ReLU+pool -> NHWC bf16 ----------
__global__ __launch_bounds__(256) void conv2_apply_k(
    const bf16* __restrict__ in, const float* __restrict__ Sacc2,
    const float* __restrict__ g, const float* __restrict__ bt,
    bf16* __restrict__ out)
{
  int t = threadIdx.x;
  __shared__ float lsc[32], lsh[32];
  if (t < 32) {
    const float invn = 1.f / (2048.f * 169.f);
    float s = 0.f, ssum = 0.f;
#pragma unroll
    for (int sl = 0; sl < 8; ++sl) {
      s += Sacc2[sl * 64 + 2 * t];
      ssum += Sacc2[sl * 64 + 2 * t + 1];
    }
    float mean = s * invn;
    float var = ssum * invn - mean * mean;
    float sc = g[t] / sqrtf(var + EPSV);
    lsc[t] = sc;
    lsh[t] = bt[t] - mean * sc;
  }
  __syncthreads();
  int idx = blockIdx.x * 256 + t;            // exactly 2048*36*4
  int img = idx / 144, r = idx - img * 144;
  int pp = r >> 2, c8 = r & 3;
  int py = pp / 6, px = pp - py * 6;
  int ip0 = (2 * py) * 13 + 2 * px;
  const bf16* bp = in + (img * 169 + ip0) * 32 + c8 * 8;
  v8s a = *(const v8s*)bp;
  v8s b = *(const v8s*)(bp + 32);
  v8s cc = *(const v8s*)(bp + 13 * 32);
  v8s d = *(const v8s*)(bp + 14 * 32);
  union { v8s v; short s[8]; bf16 h[8]; } res;
#pragma unroll
  for (int k = 0; k < 8; ++k) {
    int ch = c8 * 8 + k;
    float sc = lsc[ch], sh = lsh[ch];
    float v = fmaxf(fmaf(bs2f(a[k]), sc, sh), 0.f) + fmaxf(fmaf(bs2f(b[k]), sc, sh), 0.f)
            + fmaxf(fmaf(bs2f(cc[k]), sc, sh), 0.f) + fmaxf(fmaf(bs2f(d[k]), sc, sh), 0.f);
    res.h[k] = f2b(v * 0.25f);
  }
  *(v8s*)(out + (img * 36 + pp) * 32 + c8 * 8) = res.v;
}

// ---------- conv3 apply: LDS-shared BN params; pool + broadcast to 4 beams ----------
__global__ __launch_bounds__(256) void conv3_apply_k(
    const float* __restrict__ in, const float* __restrict__ Sacc3,
    const float* __restrict__ g, const float* __restrict__ bt,
    float* __restrict__ hs)
{
  int t = threadIdx.x;
  __shared__ float lsc[32], lsh[32];
  if (t < 32) {
    const float invn = 1.f / (2048.f * 16.f);
    float s = 0.f, ssum = 0.f;
#pragma unroll
    for (int sl = 0; sl < 8; ++sl) {
      s += Sacc3[sl * 64 + 2 * t];
      ssum += Sacc3[sl * 64 + 2 * t + 1];
    }
    float mean = s * invn;
    float var = ssum * invn - mean * mean;
    float sc = g[t] / sqrtf(var + EPSV);
    lsc[t] = sc;
    lsh[t] = bt[t] - mean * sc;
  }
  __syncthreads();
  int idx = blockIdx.x * 256 + t;            // exactly 2048*128
  int img = idx >> 7, r = idx & 127;
  int c = r >> 2, q = r & 3;
  int py = q >> 1, px = q & 1;
  int p0 = py * 8 + px * 2;
  const float* bp = in + img * 512 + c;
  float sc = lsc[c], sh = lsh[c];
  float v = (fmaxf(fmaf(bp[p0 * 32], sc, sh), 0.f)
           + fmaxf(fmaf(bp[(p0 + 1) * 32], sc, sh), 0.f)
           + fmaxf(fmaf(bp[(p0 + 4) * 32], sc, sh), 0.f)
           + fmaxf(fmaf(bp[(p0 + 5) * 32], sc, sh), 0.f)) * 0.25f;
  float* hb = hs + img * 512 + r;
  hb[0] = v; hb[128] = v; hb[256] = v; hb[384] = v;
}

// ---------- fused MoE 3 steps + head; LDS sig-table scan ----------
__global__ __launch_bounds__(256) void moe_fused_k(
    const float* __restrict__ hs, const bf16* __restrict__ Web,
    const float* __restrict__ be, const bf16* __restrict__ Wob,
    const float* __restrict__ bo, const float* __restrict__ sv,
    const int* __restrict__ cnt27, const int* __restrict__ lists,
    float* __restrict__ out)
{
  int t = threadIdx.x, lane = t & 63, wv = t >> 6;
  int m = lane & 15, kg = lane >> 4;
  __shared__ float st[4][16][132];
  __shared__ int scnt[64], stile[64];

  if (t < 64) scnt[t] = cnt27[t];
  __syncthreads();
  if (t == 0) {
    int b = 0;
#pragma unroll
    for (int s = 0; s < 64; ++s) { stile[s] = b; b += (scnt[s] + 15) >> 4; }
  }
  __syncthreads();

  int g = blockIdx.x * 4 + wv;
  int sig = -1, tile = 0, cntS = 0;
#pragma unroll
  for (int s = 0; s < 64; ++s) {
    int nt = (scnt[s] + 15) >> 4;
    if (g >= stile[s] && g < stile[s] + nt) { sig = s; tile = g - stile[s]; cntS = scnt[s]; }
  }
  if (sig < 0) return;
  const int* lp = lists + sig * 8192;
  int ra = tile * 16 + m;
  int rowA = lp[ra < cntS ? ra : cntS - 1];

  const float* hrow = hs + rowA * 128 + kg * 32;
#pragma unroll
  for (int q = 0; q < 8; ++q)
    *(float4*)&st[wv][m][kg * 32 + q * 4] = ((const float4*)hrow)[q];

  int es[3] = { sig & 3, (sig >> 2) & 3, sig >> 4 };
#pragma unroll
  for (int stp = 0; stp < 3; ++stp) {
    int e = es[stp];
    if (e == 3) continue;
    const short* wbs = (const short*)(Web + e * 16384);
    v8s afr[4];
#pragma unroll
    for (int kk = 0; kk < 4; ++kk) {
      float4 a0 = *(const float4*)&st[wv][m][kk * 32 + kg * 8];
      float4 a1 = *(const float4*)&st[wv][m][kk * 32 + kg * 8 + 4];
      afr[kk][0] = f2bs(a0.x); afr[kk][1] = f2bs(a0.y);
      afr[kk][2] = f2bs(a0.z); afr[kk][3] = f2bs(a0.w);
      afr[kk][4] = f2bs(a1.x); afr[kk][5] = f2bs(a1.y);
      afr[kk][6] = f2bs(a1.z); afr[kk][7] = f2bs(a1.w);
    }
#pragma unroll
    for (int ob = 0; ob < 8; ++ob) {
      v4f acc = {0.f, 0.f, 0.f, 0.f};
#pragma unroll
      for (int kk = 0; kk < 4; ++kk) {
        v8s bfr;
#pragma unroll
        for (int j = 0; j < 8; ++j)
          bfr[j] = wbs[(kk * 32 + kg * 8 + j) * 128 + ob * 16 + m];
        acc = __builtin_amdgcn_mfma_f32_16x16x32_bf16(afr[kk], bfr, acc, 0, 0, 0);
      }
      float bb = be[e * 128 + ob * 16 + m];
#pragma unroll
      for (int j = 0; j < 4; ++j)
        st[wv][kg * 4 + j][ob * 16 + m] = fmaxf(acc[j] + bb, 0.f);
    }
  }

  float ps = 1.f;
#pragma unroll
  for (int i = 0; i < 12; ++i) ps *= sv[i];
  const short* wos = (const short*)Wob;
  v8s afr[4];
#pragma unroll
  for (int kk = 0; kk < 4; ++kk) {
    float4 a0 = *(const float4*)&st[wv][m][kk * 32 + kg * 8];
    float4 a1 = *(const float4*)&st[wv][m][kk * 32 + kg * 8 + 4];
    afr[kk][0] = f2bs(a0.x); afr[kk][1] = f2bs(a0.y);
    afr[kk][2] = f2bs(a0.z); afr[kk][3] = f2bs(a0.w);
    afr[kk][4] = f2bs(a1.x); afr[kk][5] = f2bs(a1.y);
    afr[kk][6] = f2bs(a1.z); afr[kk][7] = f2bs(a1.w);
  }
  v4f acc = {0.f, 0.f, 0.f, 0.f};
#pragma unroll
  for (int kk = 0; kk < 4; ++kk) {
    v8s bfr;
#pragma unroll
    for (int j = 0; j < 8; ++j)
      bfr[j] = wos[(kk * 32 + kg * 8 + j) * 16 + m];
    acc = __builtin_amdgcn_mfma_f32_16x16x32_bf16(afr[kk], bfr, acc, 0, 0, 0);
  }
  if (m < 10) {
    float bov = bo[m];
#pragma unroll
    for (int j = 0; j < 4; ++j) {
      int idx = tile * 16 + kg * 4 + j;
      if (idx < cntS) out[lp[idx] * 10 + m] = (acc[j] + bov) * ps;
    }
  }
}

extern "C" void kernel_launch(void* const* d_in, const int* in_sizes, int n_in,
                              void* d_out, int out_size, void* d_ws, size_t ws_size,
                              hipStream_t stream)
{
  float* out = (float*)d_out;

  static const int EXP[19] = {2097152, 98304, 12, 288, 32, 9216, 32, 9216, 32,
                              32, 32, 32, 32, 32, 32, 49152, 384, 1280, 10};
  int bad = -1;
  if (n_in != 19) bad = 100;
  else
    for (int i = 0; i < 19; ++i)
      if (in_sizes[i] != EXP[i]) { bad = i; break; }
  if (bad >= 0) {
    fill_k<<<(out_size + 255) / 256, 256, 0, stream>>>(out, 1000.f + 10.f * bad, out_size);
    return;
  }
  const size_t NEED = 75771904;
  if (ws_size < NEED) {
    fill_k<<<(out_size + 255) / 256, 256, 0, stream>>>(
        out, 3000.f + (float)(ws_size >> 20), out_size);
    return;
  }

  const float* x    = (const float*)d_in[0];
  const float* traj = (const float*)d_in[1];
  const float* sv   = (const float*)d_in[2];
  const float* c1w  = (const float*)d_in[3];
  const float* c1b  = (const float*)d_in[4];
  const float* c2w  = (const float*)d_in[5];
  const float* c3w  = (const float*)d_in[7];
  const float* g1   = (const float*)d_in[9];
  const float* bt1  = (const float*)d_in[10];
  const float* g2   = (const float*)d_in[11];
  const float* bt2  = (const float*)d_in[12];
  const float* g3   = (const float*)d_in[13];
  const float* bt3  = (const float*)d_in[14];
  const float* We   = (const float*)d_in[15];
  const float* be   = (const float*)d_in[16];
  const float* Wo   = (const float*)d_in[17];
  const float* bo   = (const float*)d_in[18];

  char* w = (char*)d_ws;
  bf16*  pooled1  = (bf16*)(w + 0);          // NHWC bf16, 29,491,200 B
  bf16*  conv2out = (bf16*)(w + 29491200);   // NHWC bf16, 22,151,168 B
  bf16*  pooled2  = (bf16*)(w + 51642368);   // NHWC bf16, 4,718,592 B
  bf16*  Web      = (bf16*)(w + 56360960);   // 98,304 B
  float* conv3out = (float*)(w + 61079552);  // NHWC f32, 4,194,304 B
  float* hsA      = (float*)(w + 65273856);  // 4,194,304 B
  float* hsB      = (float*)(w + 69468160);  // weight staging only
  float* Macc     = (float*)(w + 73662464);  // 8 slots x 64 f32 = 2048 B
  float* Sacc2    = (float*)(w + 73664512);  // 2048 B
  float* Sacc3    = (float*)(w + 73666560);  // 2048 B
  int*   cnt27    = (int*)(w + 73668608);    // 256 B
  bf16*  Wob      = (bf16*)(w + 73670656);   // 4,096 B
  int*   lists    = (int*)(w + 73674752);    // 64*8192*4 = 2,097,152 -> end 75,771,904
  bf16*  w2b      = (bf16*)hsB;
  bf16*  w3b      = w2b + 9216;

  setup_k<<<272, 256, 0, stream>>>(c2w, c3w, We, Wo, w2b, w3b, Web, Wob,
                                   cnt27, Macc, Sacc2, Sacc3);
  front_k<<<544, 256, 0, stream>>>(traj, x, cnt27, lists, Macc);
  conv1_apply_k<<<2048, 512, 0, stream>>>(x, c1w, c1b, g1, bt1, Macc, pooled1);
  conv_mfma_k<15, 13, 169, true><<<1352, 256, 0, stream>>>(pooled1, w2b, conv2out,
                                                           Sacc2, 21632);
  conv2_apply_k<<<1152, 256, 0, stream>>>(conv2out, Sacc2, g2, bt2, pooled2);
  conv_mfma_k<6, 4, 16, false><<<512, 256, 0, stream>>>(pooled2, w3b, conv3out,
                                                        Sacc3, 2048);
  conv3_apply_k<<<1024, 256, 0, stream>>>(conv3out, Sacc3, g3, bt3, hsA);
  moe_fused_k<<<256, 256, 0, stream>>>(hsA, Web, be, Wob, bo, sv, cnt27, lists, out);
}

// Round 16
// 97.072 us; speedup vs baseline: 1.7228x; 1.0938x over previous
//
#include <hip/hip_runtime.h>
#include <hip/hip_bf16.h>

#define EPSV 1e-5f
typedef __hip_bfloat16 bf16;
typedef __attribute__((ext_vector_type(8))) short v8s;
typedef __attribute__((ext_vector_type(4))) float v4f;
__device__ __forceinline__ float b2f(bf16 v) { return __bfloat162float(v); }
__device__ __forceinline__ bf16 f2b(float v) { return __float2bfloat16(v); }
__device__ __forceinline__ float bs2f(short s) {
  return __uint_as_float(((unsigned)(unsigned short)s) << 16);
}
__device__ __forceinline__ short f2bs(float v) {
  bf16 b = __float2bfloat16(v);
  return *(short*)&b;
}

__global__ __launch_bounds__(256) void fill_k(float* __restrict__ out, float val, int n)
{
  int i = blockIdx.x * 256 + threadIdx.x;
  if (i < n) out[i] = val;
}

// ---------- setup: zero slotted accumulators/cnt; pack weights; Web; Wob ----------
__global__ __launch_bounds__(256) void setup_k(
    const float* __restrict__ w2, const float* __restrict__ w3,
    const float* __restrict__ We, const float* __restrict__ Wo,
    bf16* __restrict__ w2b, bf16* __restrict__ w3b,
    bf16* __restrict__ Web, bf16* __restrict__ Wob,
    int* __restrict__ cnt27, float* __restrict__ Macc,
    float* __restrict__ Sacc2, float* __restrict__ Sacc3)
{
  int i = blockIdx.x * 256 + threadIdx.x;
  if (i < 64) cnt27[i] = 0;
  if (i < 512) {                              // 8 slots x 64
    Macc[i] = 0.f;
    Sacc2[i] = 0.f;
    Sacc3[i] = 0.f;
  }
  if (i < 9216) {
    int oc = i / 288, r = i - oc * 288, s = r >> 5, ic = r & 31;  // [oc][s*32+ic]
    w2b[i] = f2b(w2[oc * 288 + ic * 9 + s]);
  } else if (i < 18432) {
    int j = i - 9216;
    int oc = j / 288, r = j - oc * 288, s = r >> 5, ic = r & 31;
    w3b[j] = f2b(w3[oc * 288 + ic * 9 + s]);
  } else if (i < 18432 + 49152) {
    Web[i - 18432] = f2b(We[i - 18432]);
  } else if (i < 18432 + 49152 + 2048) {
    int j = i - 18432 - 49152;               // j = k*16 + o
    int k = j >> 4, o = j & 15;
    Wob[j] = (o < 10) ? f2b(Wo[o * 128 + k]) : f2b(0.f);
  }
}

// ---------- front: blocks 0-31 = signature compaction; 32-543 = conv1 autocorr ----------
__global__ __launch_bounds__(256) void front_k(
    const float* __restrict__ traj, const float* __restrict__ x,
    int* __restrict__ cnt27, int* __restrict__ lists, float* __restrict__ Macc)
{
  int t = threadIdx.x;
  if (blockIdx.x < 32) {
    int row = blockIdx.x * 256 + t;
    __shared__ int lcnt[64], lbase[64];
    if (t < 64) lcnt[t] = 0;
    __syncthreads();
    int e[3];
#pragma unroll
    for (int s = 0; s < 3; ++s) {
      float4 tv = ((const float4*)traj)[s * 8192 + row];
      int ee = 0; float bv = tv.x;
      if (tv.y > bv) { bv = tv.y; ee = 1; }
      if (tv.z > bv) { bv = tv.z; ee = 2; }
      if (tv.w > bv) { bv = tv.w; ee = 3; }
      e[s] = ee;
    }
    int sig = e[0] + 4 * e[1] + 16 * e[2];
    int my = atomicAdd(&lcnt[sig], 1);
    __syncthreads();
    if (t < 64) lbase[t] = atomicAdd(&cnt27[t], lcnt[t]);
    __syncthreads();
    lists[sig * 8192 + lbase[sig] + my] = row;
    return;
  }
  // conv1 autocorrelation: 4 images per block
  int blk = blockIdx.x - 32;
  __shared__ __align__(16) float xs[1024];
  float M[45], S[9];
#pragma unroll
  for (int k = 0; k < 45; ++k) M[k] = 0.f;
#pragma unroll
  for (int k = 0; k < 9; ++k) S[k] = 0.f;
  for (int im = 0; im < 4; ++im) {
    int img = blk * 4 + im;
    ((float4*)xs)[t] = ((const float4*)(x + img * 1024))[t];
    __syncthreads();
    for (int p = t; p < 900; p += 256) {
      int y = p / 30, xx = p - y * 30;
      const float* r0 = xs + y * 32 + xx;
      float v[9];
      v[0] = r0[0];  v[1] = r0[1];  v[2] = r0[2];
      v[3] = r0[32]; v[4] = r0[33]; v[5] = r0[34];
      v[6] = r0[64]; v[7] = r0[65]; v[8] = r0[66];
      int idx = 0;
#pragma unroll
      for (int i = 0; i < 9; ++i) {
        S[i] += v[i];
#pragma unroll
        for (int j = i; j < 9; ++j) M[idx++] = fmaf(v[i], v[j], M[idx]);
      }
    }
    __syncthreads();
  }
  float a[54];
#pragma unroll
  for (int k = 0; k < 45; ++k) a[k] = M[k];
#pragma unroll
  for (int k = 0; k < 9; ++k) a[45 + k] = S[k];
#pragma unroll
  for (int k = 0; k < 54; ++k) {
#pragma unroll
    for (int off = 32; off; off >>= 1) a[k] += __shfl_down(a[k], off, 64);
  }
  __shared__ float red[4][54];
  int wv = t >> 6, lane = t & 63;
  if (lane == 0) {
#pragma unroll
    for (int k = 0; k < 54; ++k) red[wv][k] = a[k];
  }
  __syncthreads();
  if (t < 54)
    atomicAdd(&Macc[(blk & 7) * 64 + t], red[0][t] + red[1][t] + red[2][t] + red[3][t]);
}

// ---------- conv12 fused: block = image; conv1+BN1+pool in LDS, conv2 MFMA from LDS ----------
__global__ __launch_bounds__(512, 2) void conv12_k(
    const float* __restrict__ x, const float* __restrict__ w1,
    const float* __restrict__ b1, const float* __restrict__ g1,
    const float* __restrict__ bt1, const float* __restrict__ Macc,
    const bf16* __restrict__ w2b, bf16* __restrict__ conv2out,
    float* __restrict__ Sacc2)
{
  int img = blockIdx.x, t = threadIdx.x;
  __shared__ __align__(16) float xs[1024];
  __shared__ float Ms[54], scs[32], shs[32];
  __shared__ short plds[225 * 40];            // pooled1 [pix][40] (32 used, 8 pad)
  __shared__ float red[8][32][2];
  if (t < 256) ((float4*)xs)[t] = ((const float4*)(x + img * 1024))[t];
  if (t >= 256 && t < 310) {
    int k = t - 256;
    float s = 0.f;
#pragma unroll
    for (int sl = 0; sl < 8; ++sl) s += Macc[sl * 64 + k];
    Ms[k] = s;
  }
  __syncthreads();
  if (t < 32) {
    float w[9];
#pragma unroll
    for (int j = 0; j < 9; ++j) w[j] = w1[t * 9 + j];
    float bias = b1[t];
    float wS = 0.f;
#pragma unroll
    for (int i = 0; i < 9; ++i) wS = fmaf(w[i], Ms[45 + i], wS);
    float wMw = 0.f;
    int idx = 0;
#pragma unroll
    for (int i = 0; i < 9; ++i)
#pragma unroll
      for (int j = i; j < 9; ++j) {
        float coef = (i == j) ? 1.f : 2.f;
        wMw = fmaf(coef * w[i] * w[j], Ms[idx], wMw);
        ++idx;
      }
    const float Np = 2048.f * 900.f;
    float mean = (wS + Np * bias) / Np;
    float sumsq = wMw + 2.f * bias * wS + Np * bias * bias;
    float var = sumsq / Np - mean * mean;
    float sc = g1[t] / sqrtf(var + EPSV);
    scs[t] = sc;
    shs[t] = bt1[t] - mean * sc;
  }
  __syncthreads();
  // phase B: pooled1 -> LDS (thread = (ch, out-row))
  {
    int ch = t & 31, pg = t >> 5;            // pg 0..15, 15 used
    if (pg < 15) {
      float w[9];
#pragma unroll
      for (int j = 0; j < 9; ++j) w[j] = w1[ch * 9 + j];
      float bias = b1[ch], sc = scs[ch], sh = shs[ch];
      const float* rp = xs + 2 * pg * 32;
      float a0 = rp[0], a1 = rp[32], a2 = rp[64], a3 = rp[96];
      float b0 = rp[1], b1v = rp[33], b2 = rp[65], b3 = rp[97];
      short* orow = plds + pg * 15 * 40 + ch;
#pragma unroll
      for (int px = 0; px < 15; ++px) {
        int xb = 2 * px;
        float e0 = rp[xb + 2], e1 = rp[xb + 34], e2 = rp[xb + 66], e3 = rp[xb + 98];
        float f0 = rp[xb + 3], f1 = rp[xb + 35], f2 = rp[xb + 67], f3 = rp[xb + 99];
        float v00 = bias, v01 = bias, v10 = bias, v11 = bias;
        v00 = fmaf(a0, w[0], v00); v00 = fmaf(b0, w[1], v00); v00 = fmaf(e0, w[2], v00);
        v00 = fmaf(a1, w[3], v00); v00 = fmaf(b1v, w[4], v00); v00 = fmaf(e1, w[5], v00);
        v00 = fmaf(a2, w[6], v00); v00 = fmaf(b2, w[7], v00); v00 = fmaf(e2, w[8], v00);
        v01 = fmaf(b0, w[0], v01); v01 = fmaf(e0, w[1], v01); v01 = fmaf(f0, w[2], v01);
        v01 = fmaf(b1v, w[3], v01); v01 = fmaf(e1, w[4], v01); v01 = fmaf(f1, w[5], v01);
        v01 = fmaf(b2, w[6], v01); v01 = fmaf(e2, w[7], v01); v01 = fmaf(f2, w[8], v01);
        v10 = fmaf(a1, w[0], v10); v10 = fmaf(b1v, w[1], v10); v10 = fmaf(e1, w[2], v10);
        v10 = fmaf(a2, w[3], v10); v10 = fmaf(b2, w[4], v10); v10 = fmaf(e2, w[5], v10);
        v10 = fmaf(a3, w[6], v10); v10 = fmaf(b3, w[7], v10); v10 = fmaf(e3, w[8], v10);
        v11 = fmaf(b1v, w[0], v11); v11 = fmaf(e1, w[1], v11); v11 = fmaf(f1, w[2], v11);
        v11 = fmaf(b2, w[3], v11); v11 = fmaf(e2, w[4], v11); v11 = fmaf(f2, w[5], v11);
        v11 = fmaf(b3, w[6], v11); v11 = fmaf(e3, w[7], v11); v11 = fmaf(f3, w[8], v11);
        float r = fmaxf(fmaf(v00, sc, sh), 0.f) + fmaxf(fmaf(v01, sc, sh), 0.f)
                + fmaxf(fmaf(v10, sc, sh), 0.f) + fmaxf(fmaf(v11, sc, sh), 0.f);
        orow[px * 40] = f2bs(r * 0.25f);
        a0 = e0; a1 = e1; a2 = e2; a3 = e3;
        b0 = f0; b1v = f1; b2 = f2; b3 = f3;
      }
    }
  }
  __syncthreads();
  // phase C: conv2 MFMA from LDS pooled1
  int lane = t & 63, wv = t >> 6;
  int m = lane & 15, kg = lane >> 4;
  const short* wbs = (const short*)w2b;
  v8s bfr[9][2];
#pragma unroll
  for (int s = 0; s < 9; ++s)
#pragma unroll
    for (int ob = 0; ob < 2; ++ob)
      bfr[s][ob] = *(const v8s*)(wbs + (ob * 16 + m) * 288 + s * 32 + kg * 8);

  float rs0 = 0.f, rss0 = 0.f, rs1 = 0.f, rss1 = 0.f;
  for (int tile = wv; tile < 11; tile += 8) {
    int pix = tile * 16 + m;
    int cpix = pix < 169 ? pix : 168;
    int y = cpix / 13, xcol = cpix - y * 13;
    const short* ap = plds + (y * 15 + xcol) * 40 + kg * 8;
    v4f acc0 = {0.f, 0.f, 0.f, 0.f}, acc1 = {0.f, 0.f, 0.f, 0.f};
#pragma unroll
    for (int ky = 0; ky < 3; ++ky)
#pragma unroll
      for (int kx = 0; kx < 3; ++kx) {
        v8s a = *(const v8s*)(ap + (ky * 15 + kx) * 40);
        acc0 = __builtin_amdgcn_mfma_f32_16x16x32_bf16(a, bfr[ky * 3 + kx][0], acc0, 0, 0, 0);
        acc1 = __builtin_amdgcn_mfma_f32_16x16x32_bf16(a, bfr[ky * 3 + kx][1], acc1, 0, 0, 0);
      }
#pragma unroll
    for (int j = 0; j < 4; ++j) {
      int pr = tile * 16 + kg * 4 + j;
      if (pr < 169) {
        rs0 += acc0[j]; rss0 = fmaf(acc0[j], acc0[j], rss0);
        rs1 += acc1[j]; rss1 = fmaf(acc1[j], acc1[j], rss1);
        unsigned base = (img * 169 + pr) * 32;
        conv2out[base + m] = f2b(acc0[j]);
        conv2out[base + 16 + m] = f2b(acc1[j]);
      }
    }
  }
  rs0 += __shfl_xor(rs0, 16, 64);  rss0 += __shfl_xor(rss0, 16, 64);
  rs0 += __shfl_xor(rs0, 32, 64);  rss0 += __shfl_xor(rss0, 32, 64);
  rs1 += __shfl_xor(rs1, 16, 64);  rss1 += __shfl_xor(rss1, 16, 64);
  rs1 += __shfl_xor(rs1, 32, 64);  rss1 += __shfl_xor(rss1, 32, 64);
  if (lane < 16) {
    red[wv][lane][0] = rs0;      red[wv][lane][1] = rss0;
    red[wv][16 + lane][0] = rs1; red[wv][16 + lane][1] = rss1;
  }
  __syncthreads();
  if (t < 64) {
    int cc = t >> 1, j = t & 1;
    float s = 0.f;
#pragma unroll
    for (int w8 = 0; w8 < 8; ++w8) s += red[w8][cc][j];
    atomicAdd(&Sacc2[(img & 7) * 64 + t], s);
  }
}

// ---------- conv3 MFMA v2: wave = image; pooled2 staged in wave-private LDS ----------
__global__ __launch_bounds__(256, 2) void conv3_mfma_k(
    const bf16* __restrict__ conv2out, const bf16* __restrict__ w3b,
    const float* __restrict__ Sacc2, const float* __restrict__ g2,
    const float* __restrict__ bt2, float* __restrict__ conv3out,
    float* __restrict__ Sacc3)
{
  int t = threadIdx.x, lane = t & 63, wv = t >> 6;
  int m = lane & 15, kg = lane >> 4;
  __shared__ float lsc[32], lsh[32];
  __shared__ short plds[4][36 * 40];
  __shared__ float red[4][32][2];
  if (t < 32) {
    const float invn = 1.f / (2048.f * 169.f);
    float s = 0.f, ssum = 0.f;
#pragma unroll
    for (int sl = 0; sl < 8; ++sl) {
      s += Sacc2[sl * 64 + 2 * t];
      ssum += Sacc2[sl * 64 + 2 * t + 1];
    }
    float mean = s * invn;
    float var = ssum * invn - mean * mean;
    float sc = g2[t] / sqrtf(var + EPSV);
    lsc[t] = sc;
    lsh[t] = bt2[t] - mean * sc;
  }
  __syncthreads();
  int img = blockIdx.x * 4 + wv;
  // stage pooled2[36][32] (BN2+ReLU+pool fused) into wave-private LDS
#pragma unroll
  for (int k = 0; k < 18; ++k) {
    int e = k * 64 + lane;                    // 1152 elems
    int pp = e >> 5, c = e & 31;
    int py = pp / 6, px = pp - py * 6;
    int ip0 = (2 * py) * 13 + 2 * px;
    const bf16* bp = conv2out + (img * 169 + ip0) * 32 + c;
    float sc = lsc[c], sh = lsh[c];
    float v = fmaxf(fmaf(b2f(bp[0]), sc, sh), 0.f)
            + fmaxf(fmaf(b2f(bp[32]), sc, sh), 0.f)
            + fmaxf(fmaf(b2f(bp[13 * 32]), sc, sh), 0.f)
            + fmaxf(fmaf(b2f(bp[14 * 32]), sc, sh), 0.f);
    plds[wv][pp * 40 + c] = f2bs(v * 0.25f);
  }
  const short* wbs = (const short*)w3b;
  v8s bfr[9][2];
#pragma unroll
  for (int s = 0; s < 9; ++s)
#pragma unroll
    for (int ob = 0; ob < 2; ++ob)
      bfr[s][ob] = *(const v8s*)(wbs + (ob * 16 + m) * 288 + s * 32 + kg * 8);

  int y = m >> 2, xcol = m & 3;
  const short* ap = plds[wv] + (y * 6 + xcol) * 40 + kg * 8;
  v4f acc0 = {0.f, 0.f, 0.f, 0.f}, acc1 = {0.f, 0.f, 0.f, 0.f};
#pragma unroll
  for (int ky = 0; ky < 3; ++ky)
#pragma unroll
    for (int kx = 0; kx < 3; ++kx) {
      v8s a = *(const v8s*)(ap + (ky * 6 + kx) * 40);
      acc0 = __builtin_amdgcn_mfma_f32_16x16x32_bf16(a, bfr[ky * 3 + kx][0], acc0, 0, 0, 0);
      acc1 = __builtin_amdgcn_mfma_f32_16x16x32_bf16(a, bfr[ky * 3 + kx][1], acc1, 0, 0, 0);
    }
  float rs0 = 0.f, rss0 = 0.f, rs1 = 0.f, rss1 = 0.f;
#pragma unroll
  for (int j = 0; j < 4; ++j) {
    rs0 += acc0[j]; rss0 = fmaf(acc0[j], acc0[j], rss0);
    rs1 += acc1[j]; rss1 = fmaf(acc1[j], acc1[j], rss1);
    int pr = kg * 4 + j;                      // pixel within img
    unsigned base = (img * 16 + pr) * 32;
    float* o = conv3out;
    o[base + m] = acc0[j];
    o[base + 16 + m] = acc1[j];
  }
  rs0 += __shfl_xor(rs0, 16, 64);  rss0 += __shfl_xor(rss0, 16, 64);
  rs0 += __shfl_xor(rs0, 32, 64);  rss0 += __shfl_xor(rss0, 32, 64);
  rs1 += __shfl_xor(rs1, 16, 64);  rss1 += __shfl_xor(rss1, 16, 64);
  rs1 += __shfl_xor(rs1, 32, 64);  rss1 += __shfl_xor(rss1, 32, 64);
  if (lane < 16) {
    red[wv][lane][0] = rs0;      red[wv][lane][1] = rss0;
    red[wv][16 + lane][0] = rs1; red[wv][16 + lane][1] = rss1;
  }
  __syncthreads();
  if (t < 64) {
    int cc = t >> 1, j = t & 1;
    atomicAdd(&Sacc3[(blockIdx.x & 7) * 64 + t],
              red[0][cc][j] + red[1][cc][j] + red[2][cc][j] + red[3][cc][j]);
  }
}

// ---------- conv3 apply: LDS-shared BN params; pool + broadcast to 4 beams ----------
__global__ __launch_bounds__(256) void conv3_apply_k(
    const float* __restrict__ in, const float* __restrict__ Sacc3,
    const float* __restrict__ g, const float* __restrict__ bt,
    float* __restrict__ hs)
{
  int t = threadIdx.x;
  __shared__ float lsc[32], lsh[32];
  if (t < 32) {
    const float invn = 1.f / (2048.f * 16.f);
    float s = 0.f, ssum = 0.f;
#pragma unroll
    for (int sl = 0; sl < 8; ++sl) {
      s += Sacc3[sl * 64 + 2 * t];
      ssum += Sacc3[sl * 64 + 2 * t + 1];
    }
    float mean = s * invn;
    float var = ssum * invn - mean * mean;
    float sc = g[t] / sqrtf(var + EPSV);
    lsc[t] = sc;
    lsh[t] = bt[t] - mean * sc;
  }
  __syncthreads();
  int idx = blockIdx.x * 256 + t;            // exactly 2048*128
  int img = idx >> 7, r = idx & 127;
  int c = r >> 2, q = r & 3;
  int py = q >> 1, px = q & 1;
  int p0 = py * 8 + px * 2;
  const float* bp = in + img * 512 + c;
  float sc = lsc[c], sh = lsh[c];
  float v = (fmaxf(fmaf(bp[p0 * 32], sc, sh), 0.f)
           + fmaxf(fmaf(bp[(p0 + 1) * 32], sc, sh), 0.f)
           + fmaxf(fmaf(bp[(p0 + 4) * 32], sc, sh), 0.f)
           + fmaxf(fmaf(bp[(p0 + 5) * 32], sc, sh), 0.f)) * 0.25f;
  float* hb = hs + img * 512 + r;
  hb[0] = v; hb[128] = v; hb[256] = v; hb[384] = v;
}

// ---------- fused MoE 3 steps + head; LDS sig-table scan ----------
__global__ __launch_bounds__(256) void moe_fused_k(
    const float* __restrict__ hs, const bf16* __restrict__ Web,
    const float* __restrict__ be, const bf16* __restrict__ Wob,
    const float* __restrict__ bo, const float* __restrict__ sv,
    const int* __restrict__ cnt27, const int* __restrict__ lists,
    float* __restrict__ out)
{
  int t = threadIdx.x, lane = t & 63, wv = t >> 6;
  int m = lane & 15, kg = lane >> 4;
  __shared__ float st[4][16][132];
  __shared__ int scnt[64], stile[64];

  if (t < 64) scnt[t] = cnt27[t];
  __syncthreads();
  if (t == 0) {
    int b = 0;
#pragma unroll
    for (int s = 0; s < 64; ++s) { stile[s] = b; b += (scnt[s] + 15) >> 4; }
  }
  __syncthreads();

  int g = blockIdx.x * 4 + wv;
  int sig = -1, tile = 0, cntS = 0;
#pragma unroll
  for (int s = 0; s < 64; ++s) {
    int nt = (scnt[s] + 15) >> 4;
    if (g >= stile[s] && g < stile[s] + nt) { sig = s; tile = g - stile[s]; cntS = scnt[s]; }
  }
  if (sig < 0) return;
  const int* lp = lists + sig * 8192;
  int ra = tile * 16 + m;
  int rowA = lp[ra < cntS ? ra : cntS - 1];

  const float* hrow = hs + rowA * 128 + kg * 32;
#pragma unroll
  for (int q = 0; q < 8; ++q)
    *(float4*)&st[wv][m][kg * 32 + q * 4] = ((const float4*)hrow)[q];

  int es[3] = { sig & 3, (sig >> 2) & 3, sig >> 4 };
#pragma unroll
  for (int stp = 0; stp < 3; ++stp) {
    int e = es[stp];
    if (e == 3) continue;
    const short* wbs = (const short*)(Web + e * 16384);
    v8s afr[4];
#pragma unroll
    for (int kk = 0; kk < 4; ++kk) {
      float4 a0 = *(const float4*)&st[wv][m][kk * 32 + kg * 8];
      float4 a1 = *(const float4*)&st[wv][m][kk * 32 + kg * 8 + 4];
      afr[kk][0] = f2bs(a0.x); afr[kk][1] = f2bs(a0.y);
      afr[kk][2] = f2bs(a0.z); afr[kk][3] = f2bs(a0.w);
      afr[kk][4] = f2bs(a1.x); afr[kk][5] = f2bs(a1.y);
      afr[kk][6] = f2bs(a1.z); afr[kk][7] = f2bs(a1.w);
    }
#pragma unroll
    for (int ob = 0; ob < 8; ++ob) {
      v4f acc = {0.f, 0.f, 0.f, 0.f};
#pragma unroll
      for (int kk = 0; kk < 4; ++kk) {
        v8s bfr;
#pragma unroll
        for (int j = 0; j < 8; ++j)
          bfr[j] = wbs[(kk * 32 + kg * 8 + j) * 128 + ob * 16 + m];
        acc = __builtin_amdgcn_mfma_f32_16x16x32_bf16(afr[kk], bfr, acc, 0, 0, 0);
      }
      float bb = be[e * 128 + ob * 16 + m];
#pragma unroll
      for (int j = 0; j < 4; ++j)
        st[wv][kg * 4 + j][ob * 16 + m] = fmaxf(acc[j] + bb, 0.f);
    }
  }

  float ps = 1.f;
#pragma unroll
  for (int i = 0; i < 12; ++i) ps *= sv[i];
  const short* wos = (const short*)Wob;
  v8s afr[4];
#pragma unroll
  for (int kk = 0; kk < 4; ++kk) {
    float4 a0 = *(const float4*)&st[wv][m][kk * 32 + kg * 8];
    float4 a1 = *(const float4*)&st[wv][m][kk * 32 + kg * 8 + 4];
    afr[kk][0] = f2bs(a0.x); afr[kk][1] = f2bs(a0.y);
    afr[kk][2] = f2bs(a0.z); afr[kk][3] = f2bs(a0.w);
    afr[kk][4] = f2bs(a1.x); afr[kk][5] = f2bs(a1.y);
    afr[kk][6] = f2bs(a1.z); afr[kk][7] = f2bs(a1.w);
  }
  v4f acc = {0.f, 0.f, 0.f, 0.f};
#pragma unroll
  for (int kk = 0; kk < 4; ++kk) {
    v8s bfr;
#pragma unroll
    for (int j = 0; j < 8; ++j)
      bfr[j] = wos[(kk * 32 + kg * 8 + j) * 16 + m];
    acc = __builtin_amdgcn_mfma_f32_16x16x32_bf16(afr[kk], bfr, acc, 0, 0, 0);
  }
  if (m < 10) {
    float bov = bo[m];
#pragma unroll
    for (int j = 0; j < 4; ++j) {
      int idx = tile * 16 + kg * 4 + j;
      if (idx < cntS) out[lp[idx] * 10 + m] = (acc[j] + bov) * ps;
    }
  }
}

extern "C" void kernel_launch(void* const* d_in, const int* in_sizes, int n_in,
                              void* d_out, int out_size, void* d_ws, size_t ws_size,
                              hipStream_t stream)
{
  float* out = (float*)d_out;

  static const int EXP[19] = {2097152, 98304, 12, 288, 32, 9216, 32, 9216, 32,
                              32, 32, 32, 32, 32, 32, 49152, 384, 1280, 10};
  int bad = -1;
  if (n_in != 19) bad = 100;
  else
    for (int i = 0; i < 19; ++i)
      if (in_sizes[i] != EXP[i]) { bad = i; break; }
  if (bad >= 0) {
    fill_k<<<(out_size + 255) / 256, 256, 0, stream>>>(out, 1000.f + 10.f * bad, out_size);
    return;
  }
  const size_t NEED = 75771904;
  if (ws_size < NEED) {
    fill_k<<<(out_size + 255) / 256, 256, 0, stream>>>(
        out, 3000.f + (float)(ws_size >> 20), out_size);
    return;
  }

  const float* x    = (const float*)d_in[0];
  const float* traj = (const float*)d_in[1];
  const float* sv   = (const float*)d_in[2];
  const float* c1w  = (const float*)d_in[3];
  const float* c1b  = (const float*)d_in[4];
  const float* c2w  = (const float*)d_in[5];
  const float* c3w  = (const float*)d_in[7];
  const float* g1   = (const float*)d_in[9];
  const float* bt1  = (const float*)d_in[10];
  const float* g2   = (const float*)d_in[11];
  const float* bt2  = (const float*)d_in[12];
  const float* g3   = (const float*)d_in[13];
  const float* bt3  = (const float*)d_in[14];
  const float* We   = (const float*)d_in[15];
  const float* be   = (const float*)d_in[16];
  const float* Wo   = (const float*)d_in[17];
  const float* bo   = (const float*)d_in[18];

  char* w = (char*)d_ws;
  bf16*  conv2out = (bf16*)(w + 29491200);   // NHWC bf16, 22,151,168 B
  bf16*  Web      = (bf16*)(w + 56360960);   // 98,304 B
  float* conv3out = (float*)(w + 61079552);  // NHWC f32, 4,194,304 B
  float* hsA      = (float*)(w + 65273856);  // 4,194,304 B
  float* hsB      = (float*)(w + 69468160);  // weight staging only
  float* Macc     = (float*)(w + 73662464);  // 8 slots x 64 f32
  float* Sacc2    = (float*)(w + 73664512);
  float* Sacc3    = (float*)(w + 73666560);
  int*   cnt27    = (int*)(w + 73668608);
  bf16*  Wob      = (bf16*)(w + 73670656);
  int*   lists    = (int*)(w + 73674752);    // end 75,771,904
  bf16*  w2b      = (bf16*)hsB;
  bf16*  w3b      = w2b + 9216;

  setup_k<<<272, 256, 0, stream>>>(c2w, c3w, We, Wo, w2b, w3b, Web, Wob,
                                   cnt27, Macc, Sacc2, Sacc3);
  front_k<<<544, 256, 0, stream>>>(traj, x, cnt27, lists, Macc);
  conv12_k<<<2048, 512, 0, stream>>>(x, c1w, c1b, g1, bt1, Macc, w2b, conv2out, Sacc2);
  conv3_mfma_k<<<512, 256, 0, stream>>>(conv2out, w3b, Sacc2, g2, bt2, conv3out, Sacc3);
  conv3_apply_k<<<1024, 256, 0, stream>>>(conv3out, Sacc3, g3, bt3, hsA);
  moe_fused_k<<<256, 256, 0, stream>>>(hsA, Web, be, Wob, bo, sv, cnt27, lists, out);
}

// Round 17
// 92.954 us; speedup vs baseline: 1.7991x; 1.0443x over previous
//
#include <hip/hip_runtime.h>
#include <hip/hip_bf16.h>

#define EPSV 1e-5f
typedef __hip_bfloat16 bf16;
typedef __attribute__((ext_vector_type(8))) short v8s;
typedef __attribute__((ext_vector_type(4))) float v4f;
__device__ __forceinline__ float b2f(bf16 v) { return __bfloat162float(v); }
__device__ __forceinline__ bf16 f2b(float v) { return __float2bfloat16(v); }
__device__ __forceinline__ float bs2f(short s) {
  return __uint_as_float(((unsigned)(unsigned short)s) << 16);
}
__device__ __forceinline__ short f2bs(float v) {
  bf16 b = __float2bfloat16(v);
  return *(short*)&b;
}

__global__ __launch_bounds__(256) void fill_k(float* __restrict__ out, float val, int n)
{
  int i = blockIdx.x * 256 + threadIdx.x;
  if (i < n) out[i] = val;
}

// ---------- setup: zero slotted accumulators/cnt; pack weights; Web; Wob ----------
__global__ __launch_bounds__(256) void setup_k(
    const float* __restrict__ w2, const float* __restrict__ w3,
    const float* __restrict__ We, const float* __restrict__ Wo,
    bf16* __restrict__ w2b, bf16* __restrict__ w3b,
    bf16* __restrict__ Web, bf16* __restrict__ Wob,
    int* __restrict__ cnt27, float* __restrict__ Macc,
    float* __restrict__ Sacc2, float* __restrict__ Sacc3)
{
  int i = blockIdx.x * 256 + threadIdx.x;
  if (i < 64) cnt27[i] = 0;
  if (i < 512) {                              // 8 slots x 64
    Macc[i] = 0.f;
    Sacc2[i] = 0.f;
    Sacc3[i] = 0.f;
  }
  if (i < 9216) {
    int oc = i / 288, r = i - oc * 288, s = r >> 5, ic = r & 31;  // [oc][s*32+ic]
    w2b[i] = f2b(w2[oc * 288 + ic * 9 + s]);
  } else if (i < 18432) {
    int j = i - 9216;
    int oc = j / 288, r = j - oc * 288, s = r >> 5, ic = r & 31;
    w3b[j] = f2b(w3[oc * 288 + ic * 9 + s]);
  } else if (i < 18432 + 49152) {
    Web[i - 18432] = f2b(We[i - 18432]);
  } else if (i < 18432 + 49152 + 2048) {
    int j = i - 18432 - 49152;               // j = k*16 + o
    int k = j >> 4, o = j & 15;
    Wob[j] = (o < 10) ? f2b(Wo[o * 128 + k]) : f2b(0.f);
  }
}

// ---------- front: blocks 0-31 = signature compaction; 32-543 = conv1 autocorr ----------
__global__ __launch_bounds__(256) void front_k(
    const float* __restrict__ traj, const float* __restrict__ x,
    int* __restrict__ cnt27, int* __restrict__ lists, float* __restrict__ Macc)
{
  int t = threadIdx.x;
  if (blockIdx.x < 32) {
    int row = blockIdx.x * 256 + t;
    __shared__ int lcnt[64], lbase[64];
    if (t < 64) lcnt[t] = 0;
    __syncthreads();
    int e[3];
#pragma unroll
    for (int s = 0; s < 3; ++s) {
      float4 tv = ((const float4*)traj)[s * 8192 + row];
      int ee = 0; float bv = tv.x;
      if (tv.y > bv) { bv = tv.y; ee = 1; }
      if (tv.z > bv) { bv = tv.z; ee = 2; }
      if (tv.w > bv) { bv = tv.w; ee = 3; }
      e[s] = ee;
    }
    int sig = e[0] + 4 * e[1] + 16 * e[2];
    int my = atomicAdd(&lcnt[sig], 1);
    __syncthreads();
    if (t < 64) lbase[t] = atomicAdd(&cnt27[t], lcnt[t]);
    __syncthreads();
    lists[sig * 8192 + lbase[sig] + my] = row;
    return;
  }
  // conv1 autocorrelation: 4 images per block
  int blk = blockIdx.x - 32;
  __shared__ __align__(16) float xs[1024];
  float M[45], S[9];
#pragma unroll
  for (int k = 0; k < 45; ++k) M[k] = 0.f;
#pragma unroll
  for (int k = 0; k < 9; ++k) S[k] = 0.f;
  for (int im = 0; im < 4; ++im) {
    int img = blk * 4 + im;
    ((float4*)xs)[t] = ((const float4*)(x + img * 1024))[t];
    __syncthreads();
    for (int p = t; p < 900; p += 256) {
      int y = p / 30, xx = p - y * 30;
      const float* r0 = xs + y * 32 + xx;
      float v[9];
      v[0] = r0[0];  v[1] = r0[1];  v[2] = r0[2];
      v[3] = r0[32]; v[4] = r0[33]; v[5] = r0[34];
      v[6] = r0[64]; v[7] = r0[65]; v[8] = r0[66];
      int idx = 0;
#pragma unroll
      for (int i = 0; i < 9; ++i) {
        S[i] += v[i];
#pragma unroll
        for (int j = i; j < 9; ++j) M[idx++] = fmaf(v[i], v[j], M[idx]);
      }
    }
    __syncthreads();
  }
  float a[54];
#pragma unroll
  for (int k = 0; k < 45; ++k) a[k] = M[k];
#pragma unroll
  for (int k = 0; k < 9; ++k) a[45 + k] = S[k];
#pragma unroll
  for (int k = 0; k < 54; ++k) {
#pragma unroll
    for (int off = 32; off; off >>= 1) a[k] += __shfl_down(a[k], off, 64);
  }
  __shared__ float red[4][54];
  int wv = t >> 6, lane = t & 63;
  if (lane == 0) {
#pragma unroll
    for (int k = 0; k < 54; ++k) red[wv][k] = a[k];
  }
  __syncthreads();
  if (t < 54)
    atomicAdd(&Macc[(blk & 7) * 64 + t], red[0][t] + red[1][t] + red[2][t] + red[3][t]);
}

// ---------- conv12 fused: conv1+BN1+pool in LDS, conv2 MFMA with B-frags in LDS ----------
__global__ __launch_bounds__(512, 4) void conv12_k(
    const float* __restrict__ x, const float* __restrict__ w1,
    const float* __restrict__ b1, const float* __restrict__ g1,
    const float* __restrict__ bt1, const float* __restrict__ Macc,
    const bf16* __restrict__ w2b, bf16* __restrict__ conv2out,
    float* __restrict__ Sacc2)
{
  int img = blockIdx.x, t = threadIdx.x;
  __shared__ __align__(16) float xs[1024];
  __shared__ float Ms[54], scs[32], shs[32];
  __shared__ short plds[225 * 40];            // pooled1 [pix][40] (32 used, 8 pad)
  __shared__ __align__(16) short w2l[32 * 296]; // w2 rows padded 288->296
  __shared__ float red[8][32][2];
  if (t < 256) ((float4*)xs)[t] = ((const float4*)(x + img * 1024))[t];
  {
    const int* w2i = (const int*)w2b;         // 4608 dwords, rows of 144
    int* w2li = (int*)w2l;
#pragma unroll
    for (int k = 0; k < 9; ++k) {
      int i = k * 512 + t;
      int row = i / 144, col = i - row * 144;
      w2li[row * 148 + col] = w2i[i];
    }
  }
  if (t >= 256 && t < 310) {
    int k = t - 256;
    float s = 0.f;
#pragma unroll
    for (int sl = 0; sl < 8; ++sl) s += Macc[sl * 64 + k];
    Ms[k] = s;
  }
  __syncthreads();
  if (t < 32) {
    float w[9];
#pragma unroll
    for (int j = 0; j < 9; ++j) w[j] = w1[t * 9 + j];
    float bias = b1[t];
    float wS = 0.f;
#pragma unroll
    for (int i = 0; i < 9; ++i) wS = fmaf(w[i], Ms[45 + i], wS);
    float wMw = 0.f;
    int idx = 0;
#pragma unroll
    for (int i = 0; i < 9; ++i)
#pragma unroll
      for (int j = i; j < 9; ++j) {
        float coef = (i == j) ? 1.f : 2.f;
        wMw = fmaf(coef * w[i] * w[j], Ms[idx], wMw);
        ++idx;
      }
    const float Np = 2048.f * 900.f;
    float mean = (wS + Np * bias) / Np;
    float sumsq = wMw + 2.f * bias * wS + Np * bias * bias;
    float var = sumsq / Np - mean * mean;
    float sc = g1[t] / sqrtf(var + EPSV);
    scs[t] = sc;
    shs[t] = bt1[t] - mean * sc;
  }
  __syncthreads();
  // phase B: pooled1 -> LDS (thread = (ch, out-row))
  {
    int ch = t & 31, pg = t >> 5;            // pg 0..15, 15 used
    if (pg < 15) {
      float w[9];
#pragma unroll
      for (int j = 0; j < 9; ++j) w[j] = w1[ch * 9 + j];
      float bias = b1[ch], sc = scs[ch], sh = shs[ch];
      const float* rp = xs + 2 * pg * 32;
      float a0 = rp[0], a1 = rp[32], a2 = rp[64], a3 = rp[96];
      float b0 = rp[1], b1v = rp[33], b2 = rp[65], b3 = rp[97];
      short* orow = plds + pg * 15 * 40 + ch;
#pragma unroll
      for (int px = 0; px < 15; ++px) {
        int xb = 2 * px;
        float e0 = rp[xb + 2], e1 = rp[xb + 34], e2 = rp[xb + 66], e3 = rp[xb + 98];
        float f0 = rp[xb + 3], f1 = rp[xb + 35], f2 = rp[xb + 67], f3 = rp[xb + 99];
        float v00 = bias, v01 = bias, v10 = bias, v11 = bias;
        v00 = fmaf(a0, w[0], v00); v00 = fmaf(b0, w[1], v00); v00 = fmaf(e0, w[2], v00);
        v00 = fmaf(a1, w[3], v00); v00 = fmaf(b1v, w[4], v00); v00 = fmaf(e1, w[5], v00);
        v00 = fmaf(a2, w[6], v00); v00 = fmaf(b2, w[7], v00); v00 = fmaf(e2, w[8], v00);
        v01 = fmaf(b0, w[0], v01); v01 = fmaf(e0, w[1], v01); v01 = fmaf(f0, w[2], v01);
        v01 = fmaf(b1v, w[3], v01); v01 = fmaf(e1, w[4], v01); v01 = fmaf(f1, w[5], v01);
        v01 = fmaf(b2, w[6], v01); v01 = fmaf(e2, w[7], v01); v01 = fmaf(f2, w[8], v01);
        v10 = fmaf(a1, w[0], v10); v10 = fmaf(b1v, w[1], v10); v10 = fmaf(e1, w[2], v10);
        v10 = fmaf(a2, w[3], v10); v10 = fmaf(b2, w[4], v10); v10 = fmaf(e2, w[5], v10);
        v10 = fmaf(a3, w[6], v10); v10 = fmaf(b3, w[7], v10); v10 = fmaf(e3, w[8], v10);
        v11 = fmaf(b1v, w[0], v11); v11 = fmaf(e1, w[1], v11); v11 = fmaf(f1, w[2], v11);
        v11 = fmaf(b2, w[3], v11); v11 = fmaf(e2, w[4], v11); v11 = fmaf(f2, w[5], v11);
        v11 = fmaf(b3, w[6], v11); v11 = fmaf(e3, w[7], v11); v11 = fmaf(f3, w[8], v11);
        float r = fmaxf(fmaf(v00, sc, sh), 0.f) + fmaxf(fmaf(v01, sc, sh), 0.f)
                + fmaxf(fmaf(v10, sc, sh), 0.f) + fmaxf(fmaf(v11, sc, sh), 0.f);
        orow[px * 40] = f2bs(r * 0.25f);
        a0 = e0; a1 = e1; a2 = e2; a3 = e3;
        b0 = f0; b1v = f1; b2 = f2; b3 = f3;
      }
    }
  }
  __syncthreads();
  // phase C: conv2 MFMA; A-frags and B-frags both from LDS (no big register arrays)
  int lane = t & 63, wv = t >> 6;
  int m = lane & 15, kg = lane >> 4;
  const short* bp0 = w2l + m * 296 + kg * 8;
  const short* bp1 = w2l + (16 + m) * 296 + kg * 8;
  float rs0 = 0.f, rss0 = 0.f, rs1 = 0.f, rss1 = 0.f;
  for (int tile = wv; tile < 11; tile += 8) {
    int pix = tile * 16 + m;
    int cpix = pix < 169 ? pix : 168;
    int y = cpix / 13, xcol = cpix - y * 13;
    const short* ap = plds + (y * 15 + xcol) * 40 + kg * 8;
    v4f acc0 = {0.f, 0.f, 0.f, 0.f}, acc1 = {0.f, 0.f, 0.f, 0.f};
#pragma unroll
    for (int ky = 0; ky < 3; ++ky)
#pragma unroll
      for (int kx = 0; kx < 3; ++kx) {
        int s = ky * 3 + kx;
        v8s a = *(const v8s*)(ap + (ky * 15 + kx) * 40);
        v8s b0 = *(const v8s*)(bp0 + s * 32);
        v8s b1 = *(const v8s*)(bp1 + s * 32);
        acc0 = __builtin_amdgcn_mfma_f32_16x16x32_bf16(a, b0, acc0, 0, 0, 0);
        acc1 = __builtin_amdgcn_mfma_f32_16x16x32_bf16(a, b1, acc1, 0, 0, 0);
      }
#pragma unroll
    for (int j = 0; j < 4; ++j) {
      int pr = tile * 16 + kg * 4 + j;
      if (pr < 169) {
        rs0 += acc0[j]; rss0 = fmaf(acc0[j], acc0[j], rss0);
        rs1 += acc1[j]; rss1 = fmaf(acc1[j], acc1[j], rss1);
        unsigned base = (img * 169 + pr) * 32;
        conv2out[base + m] = f2b(acc0[j]);
        conv2out[base + 16 + m] = f2b(acc1[j]);
      }
    }
  }
  rs0 += __shfl_xor(rs0, 16, 64);  rss0 += __shfl_xor(rss0, 16, 64);
  rs0 += __shfl_xor(rs0, 32, 64);  rss0 += __shfl_xor(rss0, 32, 64);
  rs1 += __shfl_xor(rs1, 16, 64);  rss1 += __shfl_xor(rss1, 16, 64);
  rs1 += __shfl_xor(rs1, 32, 64);  rss1 += __shfl_xor(rss1, 32, 64);
  if (lane < 16) {
    red[wv][lane][0] = rs0;      red[wv][lane][1] = rss0;
    red[wv][16 + lane][0] = rs1; red[wv][16 + lane][1] = rss1;
  }
  __syncthreads();
  if (t < 64) {
    int cc = t >> 1, j = t & 1;
    float s = 0.f;
#pragma unroll
    for (int w8 = 0; w8 < 8; ++w8) s += red[w8][cc][j];
    atomicAdd(&Sacc2[(img & 7) * 64 + t], s);
  }
}

// ---------- conv3 MFMA v2: wave = image; pooled2 staged in wave-private LDS ----------
__global__ __launch_bounds__(256, 2) void conv3_mfma_k(
    const bf16* __restrict__ conv2out, const bf16* __restrict__ w3b,
    const float* __restrict__ Sacc2, const float* __restrict__ g2,
    const float* __restrict__ bt2, float* __restrict__ conv3out,
    float* __restrict__ Sacc3)
{
  int t = threadIdx.x, lane = t & 63, wv = t >> 6;
  int m = lane & 15, kg = lane >> 4;
  __shared__ float lsc[32], lsh[32];
  __shared__ short plds[4][36 * 40];
  __shared__ float red[4][32][2];
  if (t < 32) {
    const float invn = 1.f / (2048.f * 169.f);
    float s = 0.f, ssum = 0.f;
#pragma unroll
    for (int sl = 0; sl < 8; ++sl) {
      s += Sacc2[sl * 64 + 2 * t];
      ssum += Sacc2[sl * 64 + 2 * t + 1];
    }
    float mean = s * invn;
    float var = ssum * invn - mean * mean;
    float sc = g2[t] / sqrtf(var + EPSV);
    lsc[t] = sc;
    lsh[t] = bt2[t] - mean * sc;
  }
  __syncthreads();
  int img = blockIdx.x * 4 + wv;
#pragma unroll
  for (int k = 0; k < 18; ++k) {
    int e = k * 64 + lane;                    // 1152 elems
    int pp = e >> 5, c = e & 31;
    int py = pp / 6, px = pp - py * 6;
    int ip0 = (2 * py) * 13 + 2 * px;
    const bf16* bp = conv2out + (img * 169 + ip0) * 32 + c;
    float sc = lsc[c], sh = lsh[c];
    float v = fmaxf(fmaf(b2f(bp[0]), sc, sh), 0.f)
            + fmaxf(fmaf(b2f(bp[32]), sc, sh), 0.f)
            + fmaxf(fmaf(b2f(bp[13 * 32]), sc, sh), 0.f)
            + fmaxf(fmaf(b2f(bp[14 * 32]), sc, sh), 0.f);
    plds[wv][pp * 40 + c] = f2bs(v * 0.25f);
  }
  const short* wbs = (const short*)w3b;
  v8s bfr[9][2];
#pragma unroll
  for (int s = 0; s < 9; ++s)
#pragma unroll
    for (int ob = 0; ob < 2; ++ob)
      bfr[s][ob] = *(const v8s*)(wbs + (ob * 16 + m) * 288 + s * 32 + kg * 8);

  int y = m >> 2, xcol = m & 3;
  const short* ap = plds[wv] + (y * 6 + xcol) * 40 + kg * 8;
  v4f acc0 = {0.f, 0.f, 0.f, 0.f}, acc1 = {0.f, 0.f, 0.f, 0.f};
#pragma unroll
  for (int ky = 0; ky < 3; ++ky)
#pragma unroll
    for (int kx = 0; kx < 3; ++kx) {
      v8s a = *(const v8s*)(ap + (ky * 6 + kx) * 40);
      acc0 = __builtin_amdgcn_mfma_f32_16x16x32_bf16(a, bfr[ky * 3 + kx][0], acc0, 0, 0, 0);
      acc1 = __builtin_amdgcn_mfma_f32_16x16x32_bf16(a, bfr[ky * 3 + kx][1], acc1, 0, 0, 0);
    }
  float rs0 = 0.f, rss0 = 0.f, rs1 = 0.f, rss1 = 0.f;
#pragma unroll
  for (int j = 0; j < 4; ++j) {
    rs0 += acc0[j]; rss0 = fmaf(acc0[j], acc0[j], rss0);
    rs1 += acc1[j]; rss1 = fmaf(acc1[j], acc1[j], rss1);
    int pr = kg * 4 + j;                      // pixel within img
    unsigned base = (img * 16 + pr) * 32;
    float* o = conv3out;
    o[base + m] = acc0[j];
    o[base + 16 + m] = acc1[j];
  }
  rs0 += __shfl_xor(rs0, 16, 64);  rss0 += __shfl_xor(rss0, 16, 64);
  rs0 += __shfl_xor(rs0, 32, 64);  rss0 += __shfl_xor(rss0, 32, 64);
  rs1 += __shfl_xor(rs1, 16, 64);  rss1 += __shfl_xor(rss1, 16, 64);
  rs1 += __shfl_xor(rs1, 32, 64);  rss1 += __shfl_xor(rss1, 32, 64);
  if (lane < 16) {
    red[wv][lane][0] = rs0;      red[wv][lane][1] = rss0;
    red[wv][16 + lane][0] = rs1; red[wv][16 + lane][1] = rss1;
  }
  __syncthreads();
  if (t < 64) {
    int cc = t >> 1, j = t & 1;
    atomicAdd(&Sacc3[(blockIdx.x & 7) * 64 + t],
              red[0][cc][j] + red[1][cc][j] + red[2][cc][j] + red[3][cc][j]);
  }
}

// ---------- conv3 apply: LDS-shared BN params; pool + broadcast to 4 beams ----------
__global__ __launch_bounds__(256) void conv3_apply_k(
    const float* __restrict__ in, const float* __restrict__ Sacc3,
    const float* __restrict__ g, const float* __restrict__ bt,
    float* __restrict__ hs)
{
  int t = threadIdx.x;
  __shared__ float lsc[32], lsh[32];
  if (t < 32) {
    const float invn = 1.f / (2048.f * 16.f);
    float s = 0.f, ssum = 0.f;
#pragma unroll
    for (int sl = 0; sl < 8; ++sl) {
      s += Sacc3[sl * 64 + 2 * t];
      ssum += Sacc3[sl * 64 + 2 * t + 1];
    }
    float mean = s * invn;
    float var = ssum * invn - mean * mean;
    float sc = g[t] / sqrtf(var + EPSV);
    lsc[t] = sc;
    lsh[t] = bt[t] - mean * sc;
  }
  __syncthreads();
  int idx = blockIdx.x * 256 + t;            // exactly 2048*128
  int img = idx >> 7, r = idx & 127;
  int c = r >> 2, q = r & 3;
  int py = q >> 1, px = q & 1;
  int p0 = py * 8 + px * 2;
  const float* bp = in + img * 512 + c;
  float sc = lsc[c], sh = lsh[c];
  float v = (fmaxf(fmaf(bp[p0 * 32], sc, sh), 0.f)
           + fmaxf(fmaf(bp[(p0 + 1) * 32], sc, sh), 0.f)
           + fmaxf(fmaf(bp[(p0 + 4) * 32], sc, sh), 0.f)
           + fmaxf(fmaf(bp[(p0 + 5) * 32], sc, sh), 0.f)) * 0.25f;
  float* hb = hs + img * 512 + r;
  hb[0] = v; hb[128] = v; hb[256] = v; hb[384] = v;
}

// ---------- fused MoE 3 steps + head; LDS sig-table scan ----------
__global__ __launch_bounds__(256) void moe_fused_k(
    const float* __restrict__ hs, const bf16* __restrict__ Web,
    const float* __restrict__ be, const bf16* __restrict__ Wob,
    const float* __restrict__ bo, const float* __restrict__ sv,
    const int* __restrict__ cnt27, const int* __restrict__ lists,
    float* __restrict__ out)
{
  int t = threadIdx.x, lane = t & 63, wv = t >> 6;
  int m = lane & 15, kg = lane >> 4;
  __shared__ float st[4][16][132];
  __shared__ int scnt[64], stile[64];

  if (t < 64) scnt[t] = cnt27[t];
  __syncthreads();
  if (t == 0) {
    int b = 0;
#pragma unroll
    for (int s = 0; s < 64; ++s) { stile[s] = b; b += (scnt[s] + 15) >> 4; }
  }
  __syncthreads();

  int g = blockIdx.x * 4 + wv;
  int sig = -1, tile = 0, cntS = 0;
#pragma unroll
  for (int s = 0; s < 64; ++s) {
    int nt = (scnt[s] + 15) >> 4;
    if (g >= stile[s] && g < stile[s] + nt) { sig = s; tile = g - stile[s]; cntS = scnt[s]; }
  }
  if (sig < 0) return;
  const int* lp = lists + sig * 8192;
  int ra = tile * 16 + m;
  int rowA = lp[ra < cntS ? ra : cntS - 1];

  const float* hrow = hs + rowA * 128 + kg * 32;
#pragma unroll
  for (int q = 0; q < 8; ++q)
    *(float4*)&st[wv][m][kg * 32 + q * 4] = ((const float4*)hrow)[q];

  int es[3] = { sig & 3, (sig >> 2) & 3, sig >> 4 };
#pragma unroll
  for (int stp = 0; stp < 3; ++stp) {
    int e = es[stp];
    if (e == 3) continue;
    const short* wbs = (const short*)(Web + e * 16384);
    v8s afr[4];
#pragma unroll
    for (int kk = 0; kk < 4; ++kk) {
      float4 a0 = *(const float4*)&st[wv][m][kk * 32 + kg * 8];
      float4 a1 = *(const float4*)&st[wv][m][kk * 32 + kg * 8 + 4];
      afr[kk][0] = f2bs(a0.x); afr[kk][1] = f2bs(a0.y);
      afr[kk][2] = f2bs(a0.z); afr[kk][3] = f2bs(a0.w);
      afr[kk][4] = f2bs(a1.x); afr[kk][5] = f2bs(a1.y);
      afr[kk][6] = f2bs(a1.z); afr[kk][7] = f2bs(a1.w);
    }
#pragma unroll
    for (int ob = 0; ob < 8; ++ob) {
      v4f acc = {0.f, 0.f, 0.f, 0.f};
#pragma unroll
      for (int kk = 0; kk < 4; ++kk) {
        v8s bfr;
#pragma unroll
        for (int j = 0; j < 8; ++j)
          bfr[j] = wbs[(kk * 32 + kg * 8 + j) * 128 + ob * 16 + m];
        acc = __builtin_amdgcn_mfma_f32_16x16x32_bf16(afr[kk], bfr, acc, 0, 0, 0);
      }
      float bb = be[e * 128 + ob * 16 + m];
#pragma unroll
      for (int j = 0; j < 4; ++j)
        st[wv][kg * 4 + j][ob * 16 + m] = fmaxf(acc[j] + bb, 0.f);
    }
  }

  float ps = 1.f;
#pragma unroll
  for (int i = 0; i < 12; ++i) ps *= sv[i];
  const short* wos = (const short*)Wob;
  v8s afr[4];
#pragma unroll
  for (int kk = 0; kk < 4; ++kk) {
    float4 a0 = *(const float4*)&st[wv][m][kk * 32 + kg * 8];
    float4 a1 = *(const float4*)&st[wv][m][kk * 32 + kg * 8 + 4];
    afr[kk][0] = f2bs(a0.x); afr[kk][1] = f2bs(a0.y);
    afr[kk][2] = f2bs(a0.z); afr[kk][3] = f2bs(a0.w);
    afr[kk][4] = f2bs(a1.x); afr[kk][5] = f2bs(a1.y);
    afr[kk][6] = f2bs(a1.z); afr[kk][7] = f2bs(a1.w);
  }
  v4f acc = {0.f, 0.f, 0.f, 0.f};
#pragma unroll
  for (int kk = 0; kk < 4; ++kk) {
    v8s bfr;
#pragma unroll
    for (int j = 0; j < 8; ++j)
      bfr[j] = wos[(kk * 32 + kg * 8 + j) * 16 + m];
    acc = __builtin_amdgcn_mfma_f32_16x16x32_bf16(afr[kk], bfr, acc, 0, 0, 0);
  }
  if (m < 10) {
    float bov = bo[m];
#pragma unroll
    for (int j = 0; j < 4; ++j) {
      int idx = tile * 16 + kg * 4 + j;
      if (idx < cntS) out[lp[idx] * 10 + m] = (acc[j] + bov) * ps;
    }
  }
}

extern "C" void kernel_launch(void* const* d_in, const int* in_sizes, int n_in,
                              void* d_out, int out_size, void* d_ws, size_t ws_size,
                              hipStream_t stream)
{
  float* out = (float*)d_out;

  static const int EXP[19] = {2097152, 98304, 12, 288, 32, 9216, 32, 9216, 32,
                              32, 32, 32, 32, 32, 32, 49152, 384, 1280, 10};
  int bad = -1;
  if (n_in != 19) bad = 100;
  else
    for (int i = 0; i < 19; ++i)
      if (in_sizes[i] != EXP[i]) { bad = i; break; }
  if (bad >= 0) {
    fill_k<<<(out_size + 255) / 256, 256, 0, stream>>>(out, 1000.f + 10.f * bad, out_size);
    return;
  }
  const size_t NEED = 75771904;
  if (ws_size < NEED) {
    fill_k<<<(out_size + 255) / 256, 256, 0, stream>>>(
        out, 3000.f + (float)(ws_size >> 20), out_size);
    return;
  }

  const float* x    = (const float*)d_in[0];
  const float* traj = (const float*)d_in[1];
  const float* sv   = (const float*)d_in[2];
  const float* c1w  = (const float*)d_in[3];
  const float* c1b  = (const float*)d_in[4];
  const float* c2w  = (const float*)d_in[5];
  const float* c3w  = (const float*)d_in[7];
  const float* g1   = (const float*)d_in[9];
  const float* bt1  = (const float*)d_in[10];
  const float* g2   = (const float*)d_in[11];
  const float* bt2  = (const float*)d_in[12];
  const float* g3   = (const float*)d_in[13];
  const float* bt3  = (const float*)d_in[14];
  const float* We   = (const float*)d_in[15];
  const float* be   = (const float*)d_in[16];
  const float* Wo   = (const float*)d_in[17];
  const float* bo   = (const float*)d_in[18];

  char* w = (char*)d_ws;
  bf16*  conv2out = (bf16*)(w + 29491200);   // NHWC bf16, 22,151,168 B
  bf16*  Web      = (bf16*)(w + 56360960);   // 98,304 B
  float* conv3out = (float*)(w + 61079552);  // NHWC f32, 4,194,304 B
  float* hsA      = (float*)(w + 65273856);  // 4,194,304 B
  float* hsB      = (float*)(w + 69468160);  // weight staging only
  float* Macc     = (float*)(w + 73662464);  // 8 slots x 64 f32
  float* Sacc2    = (float*)(w + 73664512);
  float* Sacc3    = (float*)(w + 73666560);
  int*   cnt27    = (int*)(w + 73668608);
  bf16*  Wob      = (bf16*)(w + 73670656);
  int*   lists    = (int*)(w + 73674752);    // end 75,771,904
  bf16*  w2b      = (bf16*)hsB;
  bf16*  w3b      = w2b + 9216;

  setup_k<<<272, 256, 0, stream>>>(c2w, c3w, We, Wo, w2b, w3b, Web, Wob,
                                   cnt27, Macc, Sacc2, Sacc3);
  front_k<<<544, 256, 0, stream>>>(traj, x, cnt27, lists, Macc);
  conv12_k<<<2048, 512, 0, stream>>>(x, c1w, c1b, g1, bt1, Macc, w2b, conv2out, Sacc2);
  conv3_mfma_k<<<512, 256, 0, stream>>>(conv2out, w3b, Sacc2, g2, bt2, conv3out, Sacc3);
  conv3_apply_k<<<1024, 256, 0, stream>>>(conv3out, Sacc3, g3, bt3, hsA);
  moe_fused_k<<<256, 256, 0, stream>>>(hsA, Web, be, Wob, bo, sv, cnt27, lists, out);
}

// Round 18
// 92.750 us; speedup vs baseline: 1.8030x; 1.0022x over previous
//
#include <hip/hip_runtime.h>
#include <hip/hip_bf16.h>

#define EPSV 1e-5f
typedef __hip_bfloat16 bf16;
typedef __attribute__((ext_vector_type(8))) short v8s;
typedef __attribute__((ext_vector_type(4))) float v4f;
__device__ __forceinline__ float b2f(bf16 v) { return __bfloat162float(v); }
__device__ __forceinline__ bf16 f2b(float v) { return __float2bfloat16(v); }
__device__ __forceinline__ float bs2f(short s) {
  return __uint_as_float(((unsigned)(unsigned short)s) << 16);
}
__device__ __forceinline__ short f2bs(float v) {
  bf16 b = __float2bfloat16(v);
  return *(short*)&b;
}

__global__ __launch_bounds__(256) void fill_k(float* __restrict__ out, float val, int n)
{
  int i = blockIdx.x * 256 + threadIdx.x;
  if (i < n) out[i] = val;
}

// ---------- setup: zero slotted accumulators/cnt; pack weights; Web; Wob ----------
__global__ __launch_bounds__(256) void setup_k(
    const float* __restrict__ w2, const float* __restrict__ w3,
    const float* __restrict__ We, const float* __restrict__ Wo,
    bf16* __restrict__ w2b, bf16* __restrict__ w3b,
    bf16* __restrict__ Web, bf16* __restrict__ Wob,
    int* __restrict__ cnt27, float* __restrict__ Macc,
    float* __restrict__ Sacc2, float* __restrict__ Sacc3)
{
  int i = blockIdx.x * 256 + threadIdx.x;
  if (i < 64) cnt27[i] = 0;
  if (i < 512) {                              // 8 slots x 64
    Macc[i] = 0.f;
    Sacc2[i] = 0.f;
    Sacc3[i] = 0.f;
  }
  if (i < 9216) {
    int oc = i / 288, r = i - oc * 288, s = r >> 5, ic = r & 31;  // [oc][s*32+ic]
    w2b[i] = f2b(w2[oc * 288 + ic * 9 + s]);
  } else if (i < 18432) {
    int j = i - 9216;
    int oc = j / 288, r = j - oc * 288, s = r >> 5, ic = r & 31;
    w3b[j] = f2b(w3[oc * 288 + ic * 9 + s]);
  } else if (i < 18432 + 49152) {
    Web[i - 18432] = f2b(We[i - 18432]);
  } else if (i < 18432 + 49152 + 2048) {
    int j = i - 18432 - 49152;               // j = k*16 + o
    int k = j >> 4, o = j & 15;
    Wob[j] = (o < 10) ? f2b(Wo[o * 128 + k]) : f2b(0.f);
  }
}

// ---------- front: blocks 0-31 = signature compaction; 32-543 = conv1 autocorr ----------
__global__ __launch_bounds__(256) void front_k(
    const float* __restrict__ traj, const float* __restrict__ x,
    int* __restrict__ cnt27, int* __restrict__ lists, float* __restrict__ Macc)
{
  int t = threadIdx.x;
  if (blockIdx.x < 32) {
    int row = blockIdx.x * 256 + t;
    __shared__ int lcnt[64], lbase[64];
    if (t < 64) lcnt[t] = 0;
    __syncthreads();
    int e[3];
#pragma unroll
    for (int s = 0; s < 3; ++s) {
      float4 tv = ((const float4*)traj)[s * 8192 + row];
      int ee = 0; float bv = tv.x;
      if (tv.y > bv) { bv = tv.y; ee = 1; }
      if (tv.z > bv) { bv = tv.z; ee = 2; }
      if (tv.w > bv) { bv = tv.w; ee = 3; }
      e[s] = ee;
    }
    int sig = e[0] + 4 * e[1] + 16 * e[2];
    int my = atomicAdd(&lcnt[sig], 1);
    __syncthreads();
    if (t < 64) lbase[t] = atomicAdd(&cnt27[t], lcnt[t]);
    __syncthreads();
    lists[sig * 8192 + lbase[sig] + my] = row;
    return;
  }
  // conv1 autocorrelation: 4 images per block
  int blk = blockIdx.x - 32;
  __shared__ __align__(16) float xs[1024];
  float M[45], S[9];
#pragma unroll
  for (int k = 0; k < 45; ++k) M[k] = 0.f;
#pragma unroll
  for (int k = 0; k < 9; ++k) S[k] = 0.f;
  for (int im = 0; im < 4; ++im) {
    int img = blk * 4 + im;
    ((float4*)xs)[t] = ((const float4*)(x + img * 1024))[t];
    __syncthreads();
    for (int p = t; p < 900; p += 256) {
      int y = p / 30, xx = p - y * 30;
      const float* r0 = xs + y * 32 + xx;
      float v[9];
      v[0] = r0[0];  v[1] = r0[1];  v[2] = r0[2];
      v[3] = r0[32]; v[4] = r0[33]; v[5] = r0[34];
      v[6] = r0[64]; v[7] = r0[65]; v[8] = r0[66];
      int idx = 0;
#pragma unroll
      for (int i = 0; i < 9; ++i) {
        S[i] += v[i];
#pragma unroll
        for (int j = i; j < 9; ++j) M[idx++] = fmaf(v[i], v[j], M[idx]);
      }
    }
    __syncthreads();
  }
  float a[54];
#pragma unroll
  for (int k = 0; k < 45; ++k) a[k] = M[k];
#pragma unroll
  for (int k = 0; k < 9; ++k) a[45 + k] = S[k];
#pragma unroll
  for (int k = 0; k < 54; ++k) {
#pragma unroll
    for (int off = 32; off; off >>= 1) a[k] += __shfl_down(a[k], off, 64);
  }
  __shared__ float red[4][54];
  int wv = t >> 6, lane = t & 63;
  if (lane == 0) {
#pragma unroll
    for (int k = 0; k < 54; ++k) red[wv][k] = a[k];
  }
  __syncthreads();
  if (t < 54)
    atomicAdd(&Macc[(blk & 7) * 64 + t], red[0][t] + red[1][t] + red[2][t] + red[3][t]);
}

// ---------- conv12 fused: conv1+BN1+pool in LDS, conv2 MFMA with B-frags in LDS ----------
__global__ __launch_bounds__(512, 4) void conv12_k(
    const float* __restrict__ x, const float* __restrict__ w1,
    const float* __restrict__ b1, const float* __restrict__ g1,
    const float* __restrict__ bt1, const float* __restrict__ Macc,
    const bf16* __restrict__ w2b, bf16* __restrict__ conv2out,
    float* __restrict__ Sacc2)
{
  int img = blockIdx.x, t = threadIdx.x;
  __shared__ __align__(16) float xs[1024];
  __shared__ float Ms[54], scs[32], shs[32];
  __shared__ short plds[225 * 40];            // pooled1 [pix][40] (32 used, 8 pad)
  __shared__ __align__(16) short w2l[32 * 296]; // w2 rows padded 288->296
  __shared__ float red[8][32][2];
  if (t < 256) ((float4*)xs)[t] = ((const float4*)(x + img * 1024))[t];
  {
    const int* w2i = (const int*)w2b;         // 4608 dwords, rows of 144
    int* w2li = (int*)w2l;
#pragma unroll
    for (int k = 0; k < 9; ++k) {
      int i = k * 512 + t;
      int row = i / 144, col = i - row * 144;
      w2li[row * 148 + col] = w2i[i];
    }
  }
  if (t >= 256 && t < 310) {
    int k = t - 256;
    float s = 0.f;
#pragma unroll
    for (int sl = 0; sl < 8; ++sl) s += Macc[sl * 64 + k];
    Ms[k] = s;
  }
  __syncthreads();
  if (t < 32) {
    float w[9];
#pragma unroll
    for (int j = 0; j < 9; ++j) w[j] = w1[t * 9 + j];
    float bias = b1[t];
    float wS = 0.f;
#pragma unroll
    for (int i = 0; i < 9; ++i) wS = fmaf(w[i], Ms[45 + i], wS);
    float wMw = 0.f;
    int idx = 0;
#pragma unroll
    for (int i = 0; i < 9; ++i)
#pragma unroll
      for (int j = i; j < 9; ++j) {
        float coef = (i == j) ? 1.f : 2.f;
        wMw = fmaf(coef * w[i] * w[j], Ms[idx], wMw);
        ++idx;
      }
    const float Np = 2048.f * 900.f;
    float mean = (wS + Np * bias) / Np;
    float sumsq = wMw + 2.f * bias * wS + Np * bias * bias;
    float var = sumsq / Np - mean * mean;
    float sc = g1[t] / sqrtf(var + EPSV);
    scs[t] = sc;
    shs[t] = bt1[t] - mean * sc;
  }
  __syncthreads();
  // phase B: pooled1 -> LDS (thread = (ch, out-row)), float2 window loads
  {
    int ch = t & 31, pg = t >> 5;            // pg 0..15, 15 used
    if (pg < 15) {
      float w[9];
#pragma unroll
      for (int j = 0; j < 9; ++j) w[j] = w1[ch * 9 + j];
      float bias = b1[ch], sc = scs[ch], sh = shs[ch];
      const float* rp = xs + 2 * pg * 32;
      float2 l0 = *(const float2*)(rp);
      float2 l1 = *(const float2*)(rp + 32);
      float2 l2 = *(const float2*)(rp + 64);
      float2 l3 = *(const float2*)(rp + 96);
      float a0 = l0.x, b0 = l0.y, a1 = l1.x, b1v = l1.y;
      float a2 = l2.x, b2 = l2.y, a3 = l3.x, b3 = l3.y;
      short* orow = plds + pg * 15 * 40 + ch;
#pragma unroll
      for (int px = 0; px < 15; ++px) {
        int xb = 2 * px;
        float2 p0v = *(const float2*)(rp + xb + 2);
        float2 p1v = *(const float2*)(rp + xb + 34);
        float2 p2v = *(const float2*)(rp + xb + 66);
        float2 p3v = *(const float2*)(rp + xb + 98);
        float e0 = p0v.x, f0 = p0v.y, e1 = p1v.x, f1 = p1v.y;
        float e2 = p2v.x, f2 = p2v.y, e3 = p3v.x, f3 = p3v.y;
        float v00 = bias, v01 = bias, v10 = bias, v11 = bias;
        v00 = fmaf(a0, w[0], v00); v00 = fmaf(b0, w[1], v00); v00 = fmaf(e0, w[2], v00);
        v00 = fmaf(a1, w[3], v00); v00 = fmaf(b1v, w[4], v00); v00 = fmaf(e1, w[5], v00);
        v00 = fmaf(a2, w[6], v00); v00 = fmaf(b2, w[7], v00); v00 = fmaf(e2, w[8], v00);
        v01 = fmaf(b0, w[0], v01); v01 = fmaf(e0, w[1], v01); v01 = fmaf(f0, w[2], v01);
        v01 = fmaf(b1v, w[3], v01); v01 = fmaf(e1, w[4], v01); v01 = fmaf(f1, w[5], v01);
        v01 = fmaf(b2, w[6], v01); v01 = fmaf(e2, w[7], v01); v01 = fmaf(f2, w[8], v01);
        v10 = fmaf(a1, w[0], v10); v10 = fmaf(b1v, w[1], v10); v10 = fmaf(e1, w[2], v10);
        v10 = fmaf(a2, w[3], v10); v10 = fmaf(b2, w[4], v10); v10 = fmaf(e2, w[5], v10);
        v10 = fmaf(a3, w[6], v10); v10 = fmaf(b3, w[7], v10); v10 = fmaf(e3, w[8], v10);
        v11 = fmaf(b1v, w[0], v11); v11 = fmaf(e1, w[1], v11); v11 = fmaf(f1, w[2], v11);
        v11 = fmaf(b2, w[3], v11); v11 = fmaf(e2, w[4], v11); v11 = fmaf(f2, w[5], v11);
        v11 = fmaf(b3, w[6], v11); v11 = fmaf(e3, w[7], v11); v11 = fmaf(f3, w[8], v11);
        float r = fmaxf(fmaf(v00, sc, sh), 0.f) + fmaxf(fmaf(v01, sc, sh), 0.f)
                + fmaxf(fmaf(v10, sc, sh), 0.f) + fmaxf(fmaf(v11, sc, sh), 0.f);
        orow[px * 40] = f2bs(r * 0.25f);
        a0 = e0; a1 = e1; a2 = e2; a3 = e3;
        b0 = f0; b1v = f1; b2 = f2; b3 = f3;
      }
    }
  }
  __syncthreads();
  // phase C: conv2 MFMA; A-frags and B-frags both from LDS
  int lane = t & 63, wv = t >> 6;
  int m = lane & 15, kg = lane >> 4;
  const short* bp0 = w2l + m * 296 + kg * 8;
  const short* bp1 = w2l + (16 + m) * 296 + kg * 8;
  float rs0 = 0.f, rss0 = 0.f, rs1 = 0.f, rss1 = 0.f;
  for (int tile = wv; tile < 11; tile += 8) {
    int pix = tile * 16 + m;
    int cpix = pix < 169 ? pix : 168;
    int y = cpix / 13, xcol = cpix - y * 13;
    const short* ap = plds + (y * 15 + xcol) * 40 + kg * 8;
    v4f acc0 = {0.f, 0.f, 0.f, 0.f}, acc1 = {0.f, 0.f, 0.f, 0.f};
#pragma unroll
    for (int ky = 0; ky < 3; ++ky)
#pragma unroll
      for (int kx = 0; kx < 3; ++kx) {
        int s = ky * 3 + kx;
        v8s a = *(const v8s*)(ap + (ky * 15 + kx) * 40);
        v8s b0 = *(const v8s*)(bp0 + s * 32);
        v8s b1 = *(const v8s*)(bp1 + s * 32);
        acc0 = __builtin_amdgcn_mfma_f32_16x16x32_bf16(a, b0, acc0, 0, 0, 0);
        acc1 = __builtin_amdgcn_mfma_f32_16x16x32_bf16(a, b1, acc1, 0, 0, 0);
      }
#pragma unroll
    for (int j = 0; j < 4; ++j) {
      int pr = tile * 16 + kg * 4 + j;
      if (pr < 169) {
        rs0 += acc0[j]; rss0 = fmaf(acc0[j], acc0[j], rss0);
        rs1 += acc1[j]; rss1 = fmaf(acc1[j], acc1[j], rss1);
        unsigned base = (img * 169 + pr) * 32;
        conv2out[base + m] = f2b(acc0[j]);
        conv2out[base + 16 + m] = f2b(acc1[j]);
      }
    }
  }
  rs0 += __shfl_xor(rs0, 16, 64);  rss0 += __shfl_xor(rss0, 16, 64);
  rs0 += __shfl_xor(rs0, 32, 64);  rss0 += __shfl_xor(rss0, 32, 64);
  rs1 += __shfl_xor(rs1, 16, 64);  rss1 += __shfl_xor(rss1, 16, 64);
  rs1 += __shfl_xor(rs1, 32, 64);  rss1 += __shfl_xor(rss1, 32, 64);
  if (lane < 16) {
    red[wv][lane][0] = rs0;      red[wv][lane][1] = rss0;
    red[wv][16 + lane][0] = rs1; red[wv][16 + lane][1] = rss1;
  }
  __syncthreads();
  if (t < 64) {
    int cc = t >> 1, j = t & 1;
    float s = 0.f;
#pragma unroll
    for (int w8 = 0; w8 < 8; ++w8) s += red[w8][cc][j];
    atomicAdd(&Sacc2[(img & 7) * 64 + t], s);
  }
}

// ---------- conv3 MFMA: wave = image; pooled2 staged in wave-private LDS ----------
__global__ __launch_bounds__(256, 2) void conv3_mfma_k(
    const bf16* __restrict__ conv2out, const bf16* __restrict__ w3b,
    const float* __restrict__ Sacc2, const float* __restrict__ g2,
    const float* __restrict__ bt2, float* __restrict__ conv3out,
    float* __restrict__ Sacc3)
{
  int t = threadIdx.x, lane = t & 63, wv = t >> 6;
  int m = lane & 15, kg = lane >> 4;
  __shared__ float lsc[32], lsh[32];
  __shared__ short plds[4][36 * 40];
  __shared__ float red[4][32][2];
  if (t < 32) {
    const float invn = 1.f / (2048.f * 169.f);
    float s = 0.f, ssum = 0.f;
#pragma unroll
    for (int sl = 0; sl < 8; ++sl) {
      s += Sacc2[sl * 64 + 2 * t];
      ssum += Sacc2[sl * 64 + 2 * t + 1];
    }
    float mean = s * invn;
    float var = ssum * invn - mean * mean;
    float sc = g2[t] / sqrtf(var + EPSV);
    lsc[t] = sc;
    lsh[t] = bt2[t] - mean * sc;
  }
  __syncthreads();
  int img = blockIdx.x * 4 + wv;
#pragma unroll
  for (int k = 0; k < 18; ++k) {
    int e = k * 64 + lane;                    // 1152 elems
    int pp = e >> 5, c = e & 31;
    int py = pp / 6, px = pp - py * 6;
    int ip0 = (2 * py) * 13 + 2 * px;
    const bf16* bp = conv2out + (img * 169 + ip0) * 32 + c;
    float sc = lsc[c], sh = lsh[c];
    float v = fmaxf(fmaf(b2f(bp[0]), sc, sh), 0.f)
            + fmaxf(fmaf(b2f(bp[32]), sc, sh), 0.f)
            + fmaxf(fmaf(b2f(bp[13 * 32]), sc, sh), 0.f)
            + fmaxf(fmaf(b2f(bp[14 * 32]), sc, sh), 0.f);
    plds[wv][pp * 40 + c] = f2bs(v * 0.25f);
  }
  const short* wbs = (const short*)w3b;
  v8s bfr[9][2];
#pragma unroll
  for (int s = 0; s < 9; ++s)
#pragma unroll
    for (int ob = 0; ob < 2; ++ob)
      bfr[s][ob] = *(const v8s*)(wbs + (ob * 16 + m) * 288 + s * 32 + kg * 8);

  int y = m >> 2, xcol = m & 3;
  const short* ap = plds[wv] + (y * 6 + xcol) * 40 + kg * 8;
  v4f acc0 = {0.f, 0.f, 0.f, 0.f}, acc1 = {0.f, 0.f, 0.f, 0.f};
#pragma unroll
  for (int ky = 0; ky < 3; ++ky)
#pragma unroll
    for (int kx = 0; kx < 3; ++kx) {
      v8s a = *(const v8s*)(ap + (ky * 6 + kx) * 40);
      acc0 = __builtin_amdgcn_mfma_f32_16x16x32_bf16(a, bfr[ky * 3 + kx][0], acc0, 0, 0, 0);
      acc1 = __builtin_amdgcn_mfma_f32_16x16x32_bf16(a, bfr[ky * 3 + kx][1], acc1, 0, 0, 0);
    }
  float rs0 = 0.f, rss0 = 0.f, rs1 = 0.f, rss1 = 0.f;
#pragma unroll
  for (int j = 0; j < 4; ++j) {
    rs0 += acc0[j]; rss0 = fmaf(acc0[j], acc0[j], rss0);
    rs1 += acc1[j]; rss1 = fmaf(acc1[j], acc1[j], rss1);
    int pr = kg * 4 + j;                      // pixel within img
    unsigned base = (img * 16 + pr) * 32;
    float* o = conv3out;
    o[base + m] = acc0[j];
    o[base + 16 + m] = acc1[j];
  }
  rs0 += __shfl_xor(rs0, 16, 64);  rss0 += __shfl_xor(rss0, 16, 64);
  rs0 += __shfl_xor(rs0, 32, 64);  rss0 += __shfl_xor(rss0, 32, 64);
  rs1 += __shfl_xor(rs1, 16, 64);  rss1 += __shfl_xor(rss1, 16, 64);
  rs1 += __shfl_xor(rs1, 32, 64);  rss1 += __shfl_xor(rss1, 32, 64);
  if (lane < 16) {
    red[wv][lane][0] = rs0;      red[wv][lane][1] = rss0;
    red[wv][16 + lane][0] = rs1; red[wv][16 + lane][1] = rss1;
  }
  __syncthreads();
  if (t < 64) {
    int cc = t >> 1, j = t & 1;
    atomicAdd(&Sacc3[(blockIdx.x & 7) * 64 + t],
              red[0][cc][j] + red[1][cc][j] + red[2][cc][j] + red[3][cc][j]);
  }
}

// ---------- fused MoE: BN3+pool inline from conv3out, 3 steps + head ----------
__global__ __launch_bounds__(256) void moe_fused_k(
    const float* __restrict__ conv3out, const float* __restrict__ Sacc3,
    const float* __restrict__ g3, const float* __restrict__ bt3,
    const bf16* __restrict__ Web, const float* __restrict__ be,
    const bf16* __restrict__ Wob, const float* __restrict__ bo,
    const float* __restrict__ sv, const int* __restrict__ cnt27,
    const int* __restrict__ lists, float* __restrict__ out)
{
  int t = threadIdx.x, lane = t & 63, wv = t >> 6;
  int m = lane & 15, kg = lane >> 4;
  __shared__ float st[4][16][132];
  __shared__ int scnt[64], stile[64];
  __shared__ float lsc[32], lsh[32];

  if (t < 32) {
    const float invn = 1.f / (2048.f * 16.f);
    float s = 0.f, ssum = 0.f;
#pragma unroll
    for (int sl = 0; sl < 8; ++sl) {
      s += Sacc3[sl * 64 + 2 * t];
      ssum += Sacc3[sl * 64 + 2 * t + 1];
    }
    float mean = s * invn;
    float var = ssum * invn - mean * mean;
    float sc = g3[t] / sqrtf(var + EPSV);
    lsc[t] = sc;
    lsh[t] = bt3[t] - mean * sc;
  }
  if (t >= 64 && t < 128) scnt[t - 64] = cnt27[t - 64];
  __syncthreads();
  if (t == 0) {
    int b = 0;
#pragma unroll
    for (int s = 0; s < 64; ++s) { stile[s] = b; b += (scnt[s] + 15) >> 4; }
  }
  __syncthreads();

  int g = blockIdx.x * 4 + wv;
  int sig = -1, tile = 0, cntS = 0;
#pragma unroll
  for (int s = 0; s < 64; ++s) {
    int nt = (scnt[s] + 15) >> 4;
    if (g >= stile[s] && g < stile[s] + nt) { sig = s; tile = g - stile[s]; cntS = scnt[s]; }
  }
  if (sig < 0) return;
  const int* lp = lists + sig * 8192;
  int ra = tile * 16 + m;
  int rowA = lp[ra < cntS ? ra : cntS - 1];

  // reconstruct hs row from conv3out: BN3 + ReLU + 2x2 pool, beams share imgs
  {
    int img = rowA >> 2;
    const float* cbase = conv3out + img * 512 + kg * 8;
#pragma unroll
    for (int q4 = 0; q4 < 8; ++q4) {
      int c = kg * 8 + q4;
      const float* cp = cbase + q4;
      float sc = lsc[c], sh = lsh[c];
      float r[16];
#pragma unroll
      for (int p = 0; p < 16; ++p)
        r[p] = fmaxf(fmaf(cp[p * 32], sc, sh), 0.f);
      st[wv][m][kg * 32 + q4 * 4 + 0] = (r[0] + r[1] + r[4] + r[5]) * 0.25f;
      st[wv][m][kg * 32 + q4 * 4 + 1] = (r[2] + r[3] + r[6] + r[7]) * 0.25f;
      st[wv][m][kg * 32 + q4 * 4 + 2] = (r[8] + r[9] + r[12] + r[13]) * 0.25f;
      st[wv][m][kg * 32 + q4 * 4 + 3] = (r[10] + r[11] + r[14] + r[15]) * 0.25f;
    }
  }

  int es[3] = { sig & 3, (sig >> 2) & 3, sig >> 4 };
#pragma unroll
  for (int stp = 0; stp < 3; ++stp) {
    int e = es[stp];
    if (e == 3) continue;
    const short* wbs = (const short*)(Web + e * 16384);
    v8s afr[4];
#pragma unroll
    for (int kk = 0; kk < 4; ++kk) {
      float4 a0 = *(const float4*)&st[wv][m][kk * 32 + kg * 8];
      float4 a1 = *(const float4*)&st[wv][m][kk * 32 + kg * 8 + 4];
      afr[kk][0] = f2bs(a0.x); afr[kk][1] = f2bs(a0.y);
      afr[kk][2] = f2bs(a0.z); afr[kk][3] = f2bs(a0.w);
      afr[kk][4] = f2bs(a1.x); afr[kk][5] = f2bs(a1.y);
      afr[kk][6] = f2bs(a1.z); afr[kk][7] = f2bs(a1.w);
    }
#pragma unroll
    for (int ob = 0; ob < 8; ++ob) {
      v4f acc = {0.f, 0.f, 0.f, 0.f};
#pragma unroll
      for (int kk = 0; kk < 4; ++kk) {
        v8s bfr;
#pragma unroll
        for (int j = 0; j < 8; ++j)
          bfr[j] = wbs[(kk * 32 + kg * 8 + j) * 128 + ob * 16 + m];
        acc = __builtin_amdgcn_mfma_f32_16x16x32_bf16(afr[kk], bfr, acc, 0, 0, 0);
      }
      float bb = be[e * 128 + ob * 16 + m];
#pragma unroll
      for (int j = 0; j < 4; ++j)
        st[wv][kg * 4 + j][ob * 16 + m] = fmaxf(acc[j] + bb, 0.f);
    }
  }

  float ps = 1.f;
#pragma unroll
  for (int i = 0; i < 12; ++i) ps *= sv[i];
  const short* wos = (const short*)Wob;
  v8s afr[4];
#pragma unroll
  for (int kk = 0; kk < 4; ++kk) {
    float4 a0 = *(const float4*)&st[wv][m][kk * 32 + kg * 8];
    float4 a1 = *(const float4*)&st[wv][m][kk * 32 + kg * 8 + 4];
    afr[kk][0] = f2bs(a0.x); afr[kk][1] = f2bs(a0.y);
    afr[kk][2] = f2bs(a0.z); afr[kk][3] = f2bs(a0.w);
    afr[kk][4] = f2bs(a1.x); afr[kk][5] = f2bs(a1.y);
    afr[kk][6] = f2bs(a1.z); afr[kk][7] = f2bs(a1.w);
  }
  v4f acc = {0.f, 0.f, 0.f, 0.f};
#pragma unroll
  for (int kk = 0; kk < 4; ++kk) {
    v8s bfr;
#pragma unroll
    for (int j = 0; j < 8; ++j)
      bfr[j] = wos[(kk * 32 + kg * 8 + j) * 16 + m];
    acc = __builtin_amdgcn_mfma_f32_16x16x32_bf16(afr[kk], bfr, acc, 0, 0, 0);
  }
  if (m < 10) {
    float bov = bo[m];
#pragma unroll
    for (int j = 0; j < 4; ++j) {
      int idx = tile * 16 + kg * 4 + j;
      if (idx < cntS) out[lp[idx] * 10 + m] = (acc[j] + bov) * ps;
    }
  }
}

extern "C" void kernel_launch(void* const* d_in, const int* in_sizes, int n_in,
                              void* d_out, int out_size, void* d_ws, size_t ws_size,
                              hipStream_t stream)
{
  float* out = (float*)d_out;

  static const int EXP[19] = {2097152, 98304, 12, 288, 32, 9216, 32, 9216, 32,
                              32, 32, 32, 32, 32, 32, 49152, 384, 1280, 10};
  int bad = -1;
  if (n_in != 19) bad = 100;
  else
    for (int i = 0; i < 19; ++i)
      if (in_sizes[i] != EXP[i]) { bad = i; break; }
  if (bad >= 0) {
    fill_k<<<(out_size + 255) / 256, 256, 0, stream>>>(out, 1000.f + 10.f * bad, out_size);
    return;
  }
  const size_t NEED = 75771904;
  if (ws_size < NEED) {
    fill_k<<<(out_size + 255) / 256, 256, 0, stream>>>(
        out, 3000.f + (float)(ws_size >> 20), out_size);
    return;
  }

  const float* x    = (const float*)d_in[0];
  const float* traj = (const float*)d_in[1];
  const float* sv   = (const float*)d_in[2];
  const float* c1w  = (const float*)d_in[3];
  const float* c1b  = (const float*)d_in[4];
  const float* c2w  = (const float*)d_in[5];
  const float* c3w  = (const float*)d_in[7];
  const float* g1   = (const float*)d_in[9];
  const float* bt1  = (const float*)d_in[10];
  const float* g2   = (const float*)d_in[11];
  const float* bt2  = (const float*)d_in[12];
  const float* g3   = (const float*)d_in[13];
  const float* bt3  = (const float*)d_in[14];
  const float* We   = (const float*)d_in[15];
  const float* be   = (const float*)d_in[16];
  const float* Wo   = (const float*)d_in[17];
  const float* bo   = (const float*)d_in[18];

  char* w = (char*)d_ws;
  bf16*  conv2out = (bf16*)(w + 29491200);   // NHWC bf16, 22,151,168 B
  bf16*  Web      = (bf16*)(w + 56360960);   // 98,304 B
  float* conv3out = (float*)(w + 61079552);  // NHWC f32, 4,194,304 B
  float* hsB      = (float*)(w + 69468160);  // weight staging only
  float* Macc     = (float*)(w + 73662464);  // 8 slots x 64 f32
  float* Sacc2    = (float*)(w + 73664512);
  float* Sacc3    = (float*)(w + 73666560);
  int*   cnt27    = (int*)(w + 73668608);
  bf16*  Wob      = (bf16*)(w + 73670656);
  int*   lists    = (int*)(w + 73674752);    // end 75,771,904
  bf16*  w2b      = (bf16*)hsB;
  bf16*  w3b      = w2b + 9216;

  setup_k<<<272, 256, 0, stream>>>(c2w, c3w, We, Wo, w2b, w3b, Web, Wob,
                                   cnt27, Macc, Sacc2, Sacc3);
  front_k<<<544, 256, 0, stream>>>(traj, x, cnt27, lists, Macc);
  conv12_k<<<2048, 512, 0, stream>>>(x, c1w, c1b, g1, bt1, Macc, w2b, conv2out, Sacc2);
  conv3_mfma_k<<<512, 256, 0, stream>>>(conv2out, w3b, Sacc2, g2, bt2, conv3out, Sacc3);
  moe_fused_k<<<256, 256, 0, stream>>>(conv3out, Sacc3, g3, bt3, Web, be, Wob, bo,
                                       sv, cnt27, lists, out);
}

// Round 19
// 86.936 us; speedup vs baseline: 1.9236x; 1.0669x over previous
//
#include <hip/hip_runtime.h>
#include <hip/hip_bf16.h>

#define EPSV 1e-5f
typedef __hip_bfloat16 bf16;
typedef __attribute__((ext_vector_type(8))) short v8s;
typedef __attribute__((ext_vector_type(4))) float v4f;
__device__ __forceinline__ float b2f(bf16 v) { return __bfloat162float(v); }
__device__ __forceinline__ bf16 f2b(float v) { return __float2bfloat16(v); }
__device__ __forceinline__ float bs2f(short s) {
  return __uint_as_float(((unsigned)(unsigned short)s) << 16);
}
__device__ __forceinline__ short f2bs(float v) {
  bf16 b = __float2bfloat16(v);
  return *(short*)&b;
}

__global__ __launch_bounds__(256) void fill_k(float* __restrict__ out, float val, int n)
{
  int i = blockIdx.x * 256 + threadIdx.x;
  if (i < n) out[i] = val;
}

// ---------- setup: zero slotted accumulators/cnt; pack weights; Web; Wob ----------
__global__ __launch_bounds__(256) void setup_k(
    const float* __restrict__ w2, const float* __restrict__ w3,
    const float* __restrict__ We, const float* __restrict__ Wo,
    bf16* __restrict__ w2b, bf16* __restrict__ w3b,
    bf16* __restrict__ Web, bf16* __restrict__ Wob,
    int* __restrict__ cnt27, float* __restrict__ Macc,
    float* __restrict__ Sacc2, float* __restrict__ Sacc3)
{
  int i = blockIdx.x * 256 + threadIdx.x;
  if (i < 64) cnt27[i] = 0;
  if (i < 512) {                              // 8 slots x 64
    Macc[i] = 0.f;
    Sacc2[i] = 0.f;
    Sacc3[i] = 0.f;
  }
  if (i < 9216) {
    int oc = i / 288, r = i - oc * 288, s = r >> 5, ic = r & 31;  // [oc][s*32+ic]
    w2b[i] = f2b(w2[oc * 288 + ic * 9 + s]);
  } else if (i < 18432) {
    int j = i - 9216;
    int oc = j / 288, r = j - oc * 288, s = r >> 5, ic = r & 31;
    w3b[j] = f2b(w3[oc * 288 + ic * 9 + s]);
  } else if (i < 18432 + 49152) {
    Web[i - 18432] = f2b(We[i - 18432]);
  } else if (i < 18432 + 49152 + 2048) {
    int j = i - 18432 - 49152;               // j = k*16 + o
    int k = j >> 4, o = j & 15;
    Wob[j] = (o < 10) ? f2b(Wo[o * 128 + k]) : f2b(0.f);
  }
}

// ---------- front: blocks 0-31 = signature compaction; 32-543 = conv1 autocorr ----------
__global__ __launch_bounds__(256) void front_k(
    const float* __restrict__ traj, const float* __restrict__ x,
    int* __restrict__ cnt27, int* __restrict__ lists, float* __restrict__ Macc)
{
  int t = threadIdx.x;
  if (blockIdx.x < 32) {
    int row = blockIdx.x * 256 + t;
    __shared__ int lcnt[64], lbase[64];
    if (t < 64) lcnt[t] = 0;
    __syncthreads();
    int e[3];
#pragma unroll
    for (int s = 0; s < 3; ++s) {
      float4 tv = ((const float4*)traj)[s * 8192 + row];
      int ee = 0; float bv = tv.x;
      if (tv.y > bv) { bv = tv.y; ee = 1; }
      if (tv.z > bv) { bv = tv.z; ee = 2; }
      if (tv.w > bv) { bv = tv.w; ee = 3; }
      e[s] = ee;
    }
    int sig = e[0] + 4 * e[1] + 16 * e[2];
    int my = atomicAdd(&lcnt[sig], 1);
    __syncthreads();
    if (t < 64) lbase[t] = atomicAdd(&cnt27[t], lcnt[t]);
    __syncthreads();
    lists[sig * 8192 + lbase[sig] + my] = row;
    return;
  }
  // conv1 autocorrelation: 4 images per block
  int blk = blockIdx.x - 32;
  __shared__ __align__(16) float xs[1024];
  float M[45], S[9];
#pragma unroll
  for (int k = 0; k < 45; ++k) M[k] = 0.f;
#pragma unroll
  for (int k = 0; k < 9; ++k) S[k] = 0.f;
  for (int im = 0; im < 4; ++im) {
    int img = blk * 4 + im;
    ((float4*)xs)[t] = ((const float4*)(x + img * 1024))[t];
    __syncthreads();
    for (int p = t; p < 900; p += 256) {
      int y = p / 30, xx = p - y * 30;
      const float* r0 = xs + y * 32 + xx;
      float v[9];
      v[0] = r0[0];  v[1] = r0[1];  v[2] = r0[2];
      v[3] = r0[32]; v[4] = r0[33]; v[5] = r0[34];
      v[6] = r0[64]; v[7] = r0[65]; v[8] = r0[66];
      int idx = 0;
#pragma unroll
      for (int i = 0; i < 9; ++i) {
        S[i] += v[i];
#pragma unroll
        for (int j = i; j < 9; ++j) M[idx++] = fmaf(v[i], v[j], M[idx]);
      }
    }
    __syncthreads();
  }
  float a[54];
#pragma unroll
  for (int k = 0; k < 45; ++k) a[k] = M[k];
#pragma unroll
  for (int k = 0; k < 9; ++k) a[45 + k] = S[k];
#pragma unroll
  for (int k = 0; k < 54; ++k) {
#pragma unroll
    for (int off = 32; off; off >>= 1) a[k] += __shfl_down(a[k], off, 64);
  }
  __shared__ float red[4][54];
  int wv = t >> 6, lane = t & 63;
  if (lane == 0) {
#pragma unroll
    for (int k = 0; k < 54; ++k) red[wv][k] = a[k];
  }
  __syncthreads();
  if (t < 54)
    atomicAdd(&Macc[(blk & 7) * 64 + t], red[0][t] + red[1][t] + red[2][t] + red[3][t]);
}

// ---------- conv12 pipelined: producer waves (conv1) || consumer waves (conv2 MFMA) ----------
__global__ __launch_bounds__(512, 4) void conv12_k(
    const float* __restrict__ x, const float* __restrict__ w1,
    const float* __restrict__ b1, const float* __restrict__ g1,
    const float* __restrict__ bt1, const float* __restrict__ Macc,
    const bf16* __restrict__ w2b, bf16* __restrict__ conv2out,
    float* __restrict__ Sacc2)
{
  int t = threadIdx.x, lane = t & 63, wv = t >> 6;
  int m = lane & 15, kg = lane >> 4;
  __shared__ __align__(16) float xs[2][1024];
  __shared__ float Ms[54], scs[32], shs[32];
  __shared__ short plds[2][225 * 40];         // double-buffered pooled1 [pix][40]
  __shared__ __align__(16) short w2l[32 * 296];
  __shared__ float red[4][32][2];
  // prologue: stage w2l, Ms, BN1 params
  {
    const int* w2i = (const int*)w2b;         // 4608 dwords, rows of 144
    int* w2li = (int*)w2l;
#pragma unroll
    for (int k = 0; k < 9; ++k) {
      int i = k * 512 + t;
      int row = i / 144, col = i - row * 144;
      w2li[row * 148 + col] = w2i[i];
    }
  }
  if (t < 54) {
    float s = 0.f;
#pragma unroll
    for (int sl = 0; sl < 8; ++sl) s += Macc[sl * 64 + t];
    Ms[t] = s;
  }
  __syncthreads();
  if (t < 32) {
    float w[9];
#pragma unroll
    for (int j = 0; j < 9; ++j) w[j] = w1[t * 9 + j];
    float bias = b1[t];
    float wS = 0.f;
#pragma unroll
    for (int i = 0; i < 9; ++i) wS = fmaf(w[i], Ms[45 + i], wS);
    float wMw = 0.f;
    int idx = 0;
#pragma unroll
    for (int i = 0; i < 9; ++i)
#pragma unroll
      for (int j = i; j < 9; ++j) {
        float coef = (i == j) ? 1.f : 2.f;
        wMw = fmaf(coef * w[i] * w[j], Ms[idx], wMw);
        ++idx;
      }
    const float Np = 2048.f * 900.f;
    float mean = (wS + Np * bias) / Np;
    float sumsq = wMw + 2.f * bias * wS + Np * bias * bias;
    float var = sumsq / Np - mean * mean;
    float sc = g1[t] / sqrtf(var + EPSV);
    scs[t] = sc;
    shs[t] = bt1[t] - mean * sc;
  }
  __syncthreads();

  int img0 = blockIdx.x * 4;
  float rs0 = 0.f, rss0 = 0.f, rs1 = 0.f, rss1 = 0.f;   // consumer stats

  for (int it = 0; it <= 4; ++it) {
    // interval 1: producers stage x for img it
    if (wv < 4 && it < 4)
      ((float4*)xs[it & 1])[t] = ((const float4*)(x + (img0 + it) * 1024))[t];
    __syncthreads();
    // interval 2: producers B(it) || consumers C(it-1)
    if (wv < 4 && it < 4) {
      int ch = t & 31, rg = t >> 5;          // 256 threads: rg 0..7
      float w[9];
#pragma unroll
      for (int j = 0; j < 9; ++j) w[j] = w1[ch * 9 + j];
      float bias = b1[ch], sc = scs[ch], sh = shs[ch];
      const float* xb = xs[it & 1];
      short* pbase = plds[it & 1];
      for (int rr = rg; rr < 15; rr += 8) {
        const float* rp = xb + 2 * rr * 32;
        float2 l0 = *(const float2*)(rp);
        float2 l1 = *(const float2*)(rp + 32);
        float2 l2 = *(const float2*)(rp + 64);
        float2 l3 = *(const float2*)(rp + 96);
        float a0 = l0.x, b0 = l0.y, a1 = l1.x, b1v = l1.y;
        float a2 = l2.x, b2 = l2.y, a3 = l3.x, b3 = l3.y;
        short* orow = pbase + rr * 15 * 40 + ch;
#pragma unroll
        for (int px = 0; px < 15; ++px) {
          int xb2 = 2 * px;
          float2 p0v = *(const float2*)(rp + xb2 + 2);
          float2 p1v = *(const float2*)(rp + xb2 + 34);
          float2 p2v = *(const float2*)(rp + xb2 + 66);
          float2 p3v = *(const float2*)(rp + xb2 + 98);
          float e0 = p0v.x, f0 = p0v.y, e1 = p1v.x, f1 = p1v.y;
          float e2 = p2v.x, f2 = p2v.y, e3 = p3v.x, f3 = p3v.y;
          float v00 = bias, v01 = bias, v10 = bias, v11 = bias;
          v00 = fmaf(a0, w[0], v00); v00 = fmaf(b0, w[1], v00); v00 = fmaf(e0, w[2], v00);
          v00 = fmaf(a1, w[3], v00); v00 = fmaf(b1v, w[4], v00); v00 = fmaf(e1, w[5], v00);
          v00 = fmaf(a2, w[6], v00); v00 = fmaf(b2, w[7], v00); v00 = fmaf(e2, w[8], v00);
          v01 = fmaf(b0, w[0], v01); v01 = fmaf(e0, w[1], v01); v01 = fmaf(f0, w[2], v01);
          v01 = fmaf(b1v, w[3], v01); v01 = fmaf(e1, w[4], v01); v01 = fmaf(f1, w[5], v01);
          v01 = fmaf(b2, w[6], v01); v01 = fmaf(e2, w[7], v01); v01 = fmaf(f2, w[8], v01);
          v10 = fmaf(a1, w[0], v10); v10 = fmaf(b1v, w[1], v10); v10 = fmaf(e1, w[2], v10);
          v10 = fmaf(a2, w[3], v10); v10 = fmaf(b2, w[4], v10); v10 = fmaf(e2, w[5], v10);
          v10 = fmaf(a3, w[6], v10); v10 = fmaf(b3, w[7], v10); v10 = fmaf(e3, w[8], v10);
          v11 = fmaf(b1v, w[0], v11); v11 = fmaf(e1, w[1], v11); v11 = fmaf(f1, w[2], v11);
          v11 = fmaf(b2, w[3], v11); v11 = fmaf(e2, w[4], v11); v11 = fmaf(f2, w[5], v11);
          v11 = fmaf(b3, w[6], v11); v11 = fmaf(e3, w[7], v11); v11 = fmaf(f3, w[8], v11);
          float r = fmaxf(fmaf(v00, sc, sh), 0.f) + fmaxf(fmaf(v01, sc, sh), 0.f)
                  + fmaxf(fmaf(v10, sc, sh), 0.f) + fmaxf(fmaf(v11, sc, sh), 0.f);
          orow[px * 40] = f2bs(r * 0.25f);
          a0 = e0; a1 = e1; a2 = e2; a3 = e3;
          b0 = f0; b1v = f1; b2 = f2; b3 = f3;
        }
      }
    } else if (wv >= 4 && it > 0) {
      int cimg = img0 + it - 1;
      const short* pbase = plds[(it - 1) & 1];
      const short* bp0 = w2l + m * 296 + kg * 8;
      const short* bp1 = w2l + (16 + m) * 296 + kg * 8;
      for (int tile = wv - 4; tile < 11; tile += 4) {
        int pix = tile * 16 + m;
        int cpix = pix < 169 ? pix : 168;
        int y = cpix / 13, xcol = cpix - y * 13;
        const short* ap = pbase + (y * 15 + xcol) * 40 + kg * 8;
        v4f acc0 = {0.f, 0.f, 0.f, 0.f}, acc1 = {0.f, 0.f, 0.f, 0.f};
#pragma unroll
        for (int ky = 0; ky < 3; ++ky)
#pragma unroll
          for (int kx = 0; kx < 3; ++kx) {
            int s = ky * 3 + kx;
            v8s a = *(const v8s*)(ap + (ky * 15 + kx) * 40);
            v8s b0 = *(const v8s*)(bp0 + s * 32);
            v8s b1 = *(const v8s*)(bp1 + s * 32);
            acc0 = __builtin_amdgcn_mfma_f32_16x16x32_bf16(a, b0, acc0, 0, 0, 0);
            acc1 = __builtin_amdgcn_mfma_f32_16x16x32_bf16(a, b1, acc1, 0, 0, 0);
          }
#pragma unroll
        for (int j = 0; j < 4; ++j) {
          int pr = tile * 16 + kg * 4 + j;
          if (pr < 169) {
            rs0 += acc0[j]; rss0 = fmaf(acc0[j], acc0[j], rss0);
            rs1 += acc1[j]; rss1 = fmaf(acc1[j], acc1[j], rss1);
            unsigned base = (cimg * 169 + pr) * 32;
            conv2out[base + m] = f2b(acc0[j]);
            conv2out[base + 16 + m] = f2b(acc1[j]);
          }
        }
      }
    }
    __syncthreads();
  }

  // consumer stats reduce (producers hold zeros)
  rs0 += __shfl_xor(rs0, 16, 64);  rss0 += __shfl_xor(rss0, 16, 64);
  rs0 += __shfl_xor(rs0, 32, 64);  rss0 += __shfl_xor(rss0, 32, 64);
  rs1 += __shfl_xor(rs1, 16, 64);  rss1 += __shfl_xor(rss1, 16, 64);
  rs1 += __shfl_xor(rs1, 32, 64);  rss1 += __shfl_xor(rss1, 32, 64);
  if (wv >= 4 && lane < 16) {
    red[wv - 4][lane][0] = rs0;      red[wv - 4][lane][1] = rss0;
    red[wv - 4][16 + lane][0] = rs1; red[wv - 4][16 + lane][1] = rss1;
  }
  __syncthreads();
  if (t < 64) {
    int cc = t >> 1, j = t & 1;
    float s = red[0][cc][j] + red[1][cc][j] + red[2][cc][j] + red[3][cc][j];
    atomicAdd(&Sacc2[(blockIdx.x & 7) * 64 + t], s);
  }
}

// ---------- conv3 MFMA: wave = image; pooled2 staged in wave-private LDS ----------
__global__ __launch_bounds__(256, 2) void conv3_mfma_k(
    const bf16* __restrict__ conv2out, const bf16* __restrict__ w3b,
    const float* __restrict__ Sacc2, const float* __restrict__ g2,
    const float* __restrict__ bt2, float* __restrict__ conv3out,
    float* __restrict__ Sacc3)
{
  int t = threadIdx.x, lane = t & 63, wv = t >> 6;
  int m = lane & 15, kg = lane >> 4;
  __shared__ float lsc[32], lsh[32];
  __shared__ short plds[4][36 * 40];
  __shared__ float red[4][32][2];
  if (t < 32) {
    const float invn = 1.f / (2048.f * 169.f);
    float s = 0.f, ssum = 0.f;
#pragma unroll
    for (int sl = 0; sl < 8; ++sl) {
      s += Sacc2[sl * 64 + 2 * t];
      ssum += Sacc2[sl * 64 + 2 * t + 1];
    }
    float mean = s * invn;
    float var = ssum * invn - mean * mean;
    float sc = g2[t] / sqrtf(var + EPSV);
    lsc[t] = sc;
    lsh[t] = bt2[t] - mean * sc;
  }
  __syncthreads();
  int img = blockIdx.x * 4 + wv;
#pragma unroll
  for (int k = 0; k < 18; ++k) {
    int e = k * 64 + lane;                    // 1152 elems
    int pp = e >> 5, c = e & 31;
    int py = pp / 6, px = pp - py * 6;
    int ip0 = (2 * py) * 13 + 2 * px;
    const bf16* bp = conv2out + (img * 169 + ip0) * 32 + c;
    float sc = lsc[c], sh = lsh[c];
    float v = fmaxf(fmaf(b2f(bp[0]), sc, sh), 0.f)
            + fmaxf(fmaf(b2f(bp[32]), sc, sh), 0.f)
            + fmaxf(fmaf(b2f(bp[13 * 32]), sc, sh), 0.f)
            + fmaxf(fmaf(b2f(bp[14 * 32]), sc, sh), 0.f);
    plds[wv][pp * 40 + c] = f2bs(v * 0.25f);
  }
  const short* wbs = (const short*)w3b;
  v8s bfr[9][2];
#pragma unroll
  for (int s = 0; s < 9; ++s)
#pragma unroll
    for (int ob = 0; ob < 2; ++ob)
      bfr[s][ob] = *(const v8s*)(wbs + (ob * 16 + m) * 288 + s * 32 + kg * 8);

  int y = m >> 2, xcol = m & 3;
  const short* ap = plds[wv] + (y * 6 + xcol) * 40 + kg * 8;
  v4f acc0 = {0.f, 0.f, 0.f, 0.f}, acc1 = {0.f, 0.f, 0.f, 0.f};
#pragma unroll
  for (int ky = 0; ky < 3; ++ky)
#pragma unroll
    for (int kx = 0; kx < 3; ++kx) {
      v8s a = *(const v8s*)(ap + (ky * 6 + kx) * 40);
      acc0 = __builtin_amdgcn_mfma_f32_16x16x32_bf16(a, bfr[ky * 3 + kx][0], acc0, 0, 0, 0);
      acc1 = __builtin_amdgcn_mfma_f32_16x16x32_bf16(a, bfr[ky * 3 + kx][1], acc1, 0, 0, 0);
    }
  float rs0 = 0.f, rss0 = 0.f, rs1 = 0.f, rss1 = 0.f;
#pragma unroll
  for (int j = 0; j < 4; ++j) {
    rs0 += acc0[j]; rss0 = fmaf(acc0[j], acc0[j], rss0);
    rs1 += acc1[j]; rss1 = fmaf(acc1[j], acc1[j], rss1);
    int pr = kg * 4 + j;                      // pixel within img
    unsigned base = (img * 16 + pr) * 32;
    float* o = conv3out;
    o[base + m] = acc0[j];
    o[base + 16 + m] = acc1[j];
  }
  rs0 += __shfl_xor(rs0, 16, 64);  rss0 += __shfl_xor(rss0, 16, 64);
  rs0 += __shfl_xor(rs0, 32, 64);  rss0 += __shfl_xor(rss0, 32, 64);
  rs1 += __shfl_xor(rs1, 16, 64);  rss1 += __shfl_xor(rss1, 16, 64);
  rs1 += __shfl_xor(rs1, 32, 64);  rss1 += __shfl_xor(rss1, 32, 64);
  if (lane < 16) {
    red[wv][lane][0] = rs0;      red[wv][lane][1] = rss0;
    red[wv][16 + lane][0] = rs1; red[wv][16 + lane][1] = rss1;
  }
  __syncthreads();
  if (t < 64) {
    int cc = t >> 1, j = t & 1;
    atomicAdd(&Sacc3[(blockIdx.x & 7) * 64 + t],
              red[0][cc][j] + red[1][cc][j] + red[2][cc][j] + red[3][cc][j]);
  }
}

// ---------- fused MoE: BN3+pool inline from conv3out, 3 steps + head ----------
__global__ __launch_bounds__(256) void moe_fused_k(
    const float* __restrict__ conv3out, const float* __restrict__ Sacc3,
    const float* __restrict__ g3, const float* __restrict__ bt3,
    const bf16* __restrict__ Web, const float* __restrict__ be,
    const bf16* __restrict__ Wob, const float* __restrict__ bo,
    const float* __restrict__ sv, const int* __restrict__ cnt27,
    const int* __restrict__ lists, float* __restrict__ out)
{
  int t = threadIdx.x, lane = t & 63, wv = t >> 6;
  int m = lane & 15, kg = lane >> 4;
  __shared__ float st[4][16][132];
  __shared__ int scnt[64], stile[64];
  __shared__ float lsc[32], lsh[32];

  if (t < 32) {
    const float invn = 1.f / (2048.f * 16.f);
    float s = 0.f, ssum = 0.f;
#pragma unroll
    for (int sl = 0; sl < 8; ++sl) {
      s += Sacc3[sl * 64 + 2 * t];
      ssum += Sacc3[sl * 64 + 2 * t + 1];
    }
    float mean = s * invn;
    float var = ssum * invn - mean * mean;
    float sc = g3[t] / sqrtf(var + EPSV);
    lsc[t] = sc;
    lsh[t] = bt3[t] - mean * sc;
  }
  if (t >= 64 && t < 128) scnt[t - 64] = cnt27[t - 64];
  __syncthreads();
  if (t == 0) {
    int b = 0;
#pragma unroll
    for (int s = 0; s < 64; ++s) { stile[s] = b; b += (scnt[s] + 15) >> 4; }
  }
  __syncthreads();

  int g = blockIdx.x * 4 + wv;
  int sig = -1, tile = 0, cntS = 0;
#pragma unroll
  for (int s = 0; s < 64; ++s) {
    int nt = (scnt[s] + 15) >> 4;
    if (g >= stile[s] && g < stile[s] + nt) { sig = s; tile = g - stile[s]; cntS = scnt[s]; }
  }
  if (sig < 0) return;
  const int* lp = lists + sig * 8192;
  int ra = tile * 16 + m;
  int rowA = lp[ra < cntS ? ra : cntS - 1];

  // reconstruct hs row from conv3out: BN3 + ReLU + 2x2 pool, beams share imgs
  {
    int img = rowA >> 2;
    const float* cbase = conv3out + img * 512 + kg * 8;
#pragma unroll
    for (int q4 = 0; q4 < 8; ++q4) {
      int c = kg * 8 + q4;
      const float* cp = cbase + q4;
      float sc = lsc[c], sh = lsh[c];
      float r[16];
#pragma unroll
      for (int p = 0; p < 16; ++p)
        r[p] = fmaxf(fmaf(cp[p * 32], sc, sh), 0.f);
      st[wv][m][kg * 32 + q4 * 4 + 0] = (r[0] + r[1] + r[4] + r[5]) * 0.25f;
      st[wv][m][kg * 32 + q4 * 4 + 1] = (r[2] + r[3] + r[6] + r[7]) * 0.25f;
      st[wv][m][kg * 32 + q4 * 4 + 2] = (r[8] + r[9] + r[12] + r[13]) * 0.25f;
      st[wv][m][kg * 32 + q4 * 4 + 3] = (r[10] + r[11] + r[14] + r[15]) * 0.25f;
    }
  }

  int es[3] = { sig & 3, (sig >> 2) & 3, sig >> 4 };
#pragma unroll
  for (int stp = 0; stp < 3; ++stp) {
    int e = es[stp];
    if (e == 3) continue;
    const short* wbs = (const short*)(Web + e * 16384);
    v8s afr[4];
#pragma unroll
    for (int kk = 0; kk < 4; ++kk) {
      float4 a0 = *(const float4*)&st[wv][m][kk * 32 + kg * 8];
      float4 a1 = *(const float4*)&st[wv][m][kk * 32 + kg * 8 + 4];
      afr[kk][0] = f2bs(a0.x); afr[kk][1] = f2bs(a0.y);
      afr[kk][2] = f2bs(a0.z); afr[kk][3] = f2bs(a0.w);
      afr[kk][4] = f2bs(a1.x); afr[kk][5] = f2bs(a1.y);
      afr[kk][6] = f2bs(a1.z); afr[kk][7] = f2bs(a1.w);
    }
#pragma unroll
    for (int ob = 0; ob < 8; ++ob) {
      v4f acc = {0.f, 0.f, 0.f, 0.f};
#pragma unroll
      for (int kk = 0; kk < 4; ++kk) {
        v8s bfr;
#pragma unroll
        for (int j = 0; j < 8; ++j)
          bfr[j] = wbs[(kk * 32 + kg * 8 + j) * 128 + ob * 16 + m];
        acc = __builtin_amdgcn_mfma_f32_16x16x32_bf16(afr[kk], bfr, acc, 0, 0, 0);
      }
      float bb = be[e * 128 + ob * 16 + m];
#pragma unroll
      for (int j = 0; j < 4; ++j)
        st[wv][kg * 4 + j][ob * 16 + m] = fmaxf(acc[j] + bb, 0.f);
    }
  }

  float ps = 1.f;
#pragma unroll
  for (int i = 0; i < 12; ++i) ps *= sv[i];
  const short* wos = (const short*)Wob;
  v8s afr[4];
#pragma unroll
  for (int kk = 0; kk < 4; ++kk) {
    float4 a0 = *(const float4*)&st[wv][m][kk * 32 + kg * 8];
    float4 a1 = *(const float4*)&st[wv][m][kk * 32 + kg * 8 + 4];
    afr[kk][0] = f2bs(a0.x); afr[kk][1] = f2bs(a0.y);
    afr[kk][2] = f2bs(a0.z); afr[kk][3] = f2bs(a0.w);
    afr[kk][4] = f2bs(a1.x); afr[kk][5] = f2bs(a1.y);
    afr[kk][6] = f2bs(a1.z); afr[kk][7] = f2bs(a1.w);
  }
  v4f acc = {0.f, 0.f, 0.f, 0.f};
#pragma unroll
  for (int kk = 0; kk < 4; ++kk) {
    v8s bfr;
#pragma unroll
    for (int j = 0; j < 8; ++j)
      bfr[j] = wos[(kk * 32 + kg * 8 + j) * 16 + m];
    acc = __builtin_amdgcn_mfma_f32_16x16x32_bf16(afr[kk], bfr, acc, 0, 0, 0);
  }
  if (m < 10) {
    float bov = bo[m];
#pragma unroll
    for (int j = 0; j < 4; ++j) {
      int idx = tile * 16 + kg * 4 + j;
      if (idx < cntS) out[lp[idx] * 10 + m] = (acc[j] + bov) * ps;
    }
  }
}

extern "C" void kernel_launch(void* const* d_in, const int* in_sizes, int n_in,
                              void* d_out, int out_size, void* d_ws, size_t ws_size,
                              hipStream_t stream)
{
  float* out = (float*)d_out;

  static const int EXP[19] = {2097152, 98304, 12, 288, 32, 9216, 32, 9216, 32,
                              32, 32, 32, 32, 32, 32, 49152, 384, 1280, 10};
  int bad = -1;
  if (n_in != 19) bad = 100;
  else
    for (int i = 0; i < 19; ++i)
      if (in_sizes[i] != EXP[i]) { bad = i; break; }
  if (bad >= 0) {
    fill_k<<<(out_size + 255) / 256, 256, 0, stream>>>(out, 1000.f + 10.f * bad, out_size);
    return;
  }
  const size_t NEED = 75771904;
  if (ws_size < NEED) {
    fill_k<<<(out_size + 255) / 256, 256, 0, stream>>>(
        out, 3000.f + (float)(ws_size >> 20), out_size);
    return;
  }

  const float* x    = (const float*)d_in[0];
  const float* traj = (const float*)d_in[1];
  const float* sv   = (const float*)d_in[2];
  const float* c1w  = (const float*)d_in[3];
  const float* c1b  = (const float*)d_in[4];
  const float* c2w  = (const float*)d_in[5];
  const float* c3w  = (const float*)d_in[7];
  const float* g1   = (const float*)d_in[9];
  const float* bt1  = (const float*)d_in[10];
  const float* g2   = (const float*)d_in[11];
  const float* bt2  = (const float*)d_in[12];
  const float* g3   = (const float*)d_in[13];
  const float* bt3  = (const float*)d_in[14];
  const float* We   = (const float*)d_in[15];
  const float* be   = (const float*)d_in[16];
  const float* Wo   = (const float*)d_in[17];
  const float* bo   = (const float*)d_in[18];

  char* w = (char*)d_ws;
  bf16*  conv2out = (bf16*)(w + 29491200);   // NHWC bf16, 22,151,168 B
  bf16*  Web      = (bf16*)(w + 56360960);   // 98,304 B
  float* conv3out = (float*)(w + 61079552);  // NHWC f32, 4,194,304 B
  float* hsB      = (float*)(w + 69468160);  // weight staging only
  float* Macc     = (float*)(w + 73662464);  // 8 slots x 64 f32
  float* Sacc2    = (float*)(w + 73664512);
  float* Sacc3    = (float*)(w + 73666560);
  int*   cnt27    = (int*)(w + 73668608);
  bf16*  Wob      = (bf16*)(w + 73670656);
  int*   lists    = (int*)(w + 73674752);    // end 75,771,904
  bf16*  w2b      = (bf16*)hsB;
  bf16*  w3b      = w2b + 9216;

  setup_k<<<272, 256, 0, stream>>>(c2w, c3w, We, Wo, w2b, w3b, Web, Wob,
                                   cnt27, Macc, Sacc2, Sacc3);
  front_k<<<544, 256, 0, stream>>>(traj, x, cnt27, lists, Macc);
  conv12_k<<<512, 512, 0, stream>>>(x, c1w, c1b, g1, bt1, Macc, w2b, conv2out, Sacc2);
  conv3_mfma_k<<<512, 256, 0, stream>>>(conv2out, w3b, Sacc2, g2, bt2, conv3out, Sacc3);
  moe_fused_k<<<256, 256, 0, stream>>>(conv3out, Sacc3, g3, bt3, Web, be, Wob, bo,
                                       sv, cnt27, lists, out);
}